// Round 7
// baseline (4092.673 us; speedup 1.0000x reference)
//
#include <hip/hip_runtime.h>

#define NN 16384
#define NE 131072
#define HH 128

typedef unsigned short u16;
typedef unsigned int u32;
typedef __attribute__((ext_vector_type(8))) short short8;
typedef __attribute__((ext_vector_type(4))) float f32x4;
typedef __attribute__((ext_vector_type(2))) float f32x2;
typedef __attribute__((ext_vector_type(2))) u32 u32x2;

__device__ __forceinline__ float b2f(u16 u){ u32 i=((u32)u)<<16; float f; __builtin_memcpy(&f,&i,4); return f; }
__device__ __forceinline__ u16 f2b(float f){ u32 i; __builtin_memcpy(&i,&f,4); u32 r=(i+0x7fffu+((i>>16)&1u))>>16; return (u16)r; }
__device__ __forceinline__ float blo(u32 v){ return b2f((u16)(v&0xffffu)); }
__device__ __forceinline__ float bhi(u32 v){ return b2f((u16)(v>>16)); }
__device__ __forceinline__ u32 pk(float a, float b){ return (u32)f2b(a) | ((u32)f2b(b)<<16); }
__device__ __forceinline__ float siluf(float x){ return x/(1.f+__expf(-x)); }

// ws byte layout (total ~101.2 MB):
//   0          : vmsg [E,128] bf16 (32MB, edge1->edge2)
//   33554432   : Y [3N,256] bf16 (dead after edge1) -> vacc f32 [3N,128] (memset after edge1)
//   58720256   : xn [N,128] bf16 (dead after qkv)   -> xacc f32 [N,128]  (memset after edge1)
//   67108864   : vec3 [3N,128] bf16 (until update)
//   79691776   : qkv [N,384] bf16 (until edge1)
//   92274688   : vdf [N,128] f32 (until update)
//   100663296  : params bf16 (~545KB)
#define PBASE 50331648u   // u16 units = byte 100,663,296
enum : unsigned {
  O_Wq=PBASE+0, O_Wk=PBASE+16384, O_Wv=PBASE+32768, O_Wdk=PBASE+49152,
  O_Wdv=PBASE+65536, O_Wf=PBASE+81920, O_Wwsrc=PBASE+98304, O_Wwtrg=PBASE+114688,
  O_Wvec=PBASE+131072, O_Ws=PBASE+180224, O_Wo=PBASE+212992, O_Wagg=PBASE+262144,
  O_bq=PBASE+270336, O_bk=PBASE+270464, O_bv=PBASE+270592, O_bdk=PBASE+270720,
  O_bdv=PBASE+270848, O_bs=PBASE+270976, O_bo=PBASE+271232, O_bf=PBASE+271616,
  O_lng=PBASE+271744, O_lnb=PBASE+271872, O_agg=PBASE+272000
};

struct Seg { const float* s; u32 off; u32 n; };
struct Pack { Seg d[25]; int cnt; };

// ---------------- f32 -> bf16 conversion (params only) ----------------
__global__ __launch_bounds__(256) void k_cvt(Pack p, u16* __restrict__ base){
  int tid = blockIdx.x*blockDim.x + threadIdx.x;
  int stride = gridDim.x*blockDim.x;
  for (int s=0; s<p.cnt; ++s){
    const float* src = p.d[s].s;
    u16* dst = base + p.d[s].off;
    int n = (int)p.d[s].n, n4 = n>>2;
    const f32x4* s4 = (const f32x4*)src;
    for (int i=tid; i<n4; i+=stride){
      f32x4 v = s4[i];
      u32x2 o; o[0] = pk(v[0], v[1]); o[1] = pk(v[2], v[3]);
      *(u32x2*)(dst + 4*(size_t)i) = o;
    }
    for (int i = n4*4 + tid; i < n; i += stride) dst[i] = f2b(src[i]);
  }
}

// one 16x16 output tile: C[r,c] = sum_k A[r,k]*W[c,k]; A,W bf16 row-major.
template<int NK>
__device__ __forceinline__ f32x4 mm16(const u16* A, int lda, const u16* W, int ldw, f32x4 acc){
  int lane = threadIdx.x & 63;
  const u16* pa = A + (lane & 15)*lda + ((lane>>4)<<3);
  const u16* pw = W + (lane & 15)*ldw + ((lane>>4)<<3);
#pragma unroll
  for (int kc = 0; kc < NK; ++kc){
    short8 a = *(const short8*)(pa + kc*32);
    short8 b = *(const short8*)(pw + kc*32);
    acc = __builtin_amdgcn_mfma_f32_16x16x32_bf16(a, b, acc, 0, 0, 0);
  }
  return acc;
}

// ---------------- LayerNorm (f32 in -> bf16 out) ----------------
__global__ __launch_bounds__(256) void k_ln(const float* __restrict__ x, const u16* __restrict__ pb,
                                            u16* __restrict__ xn){
  int wid = threadIdx.x>>6, lane = threadIdx.x & 63;
  int n = blockIdx.x*4 + wid;
  f32x2 v = *(const f32x2*)(x + (size_t)n*HH + 2*lane);
  float a0 = v[0], a1 = v[1];
  float s = a0 + a1;
#pragma unroll
  for (int m=32; m; m>>=1) s += __shfl_xor(s, m);
  float mu = s*(1.f/128.f);
  float d0 = a0-mu, d1 = a1-mu;
  float vs = d0*d0 + d1*d1;
#pragma unroll
  for (int m=32; m; m>>=1) vs += __shfl_xor(vs, m);
  float rs = rsqrtf(vs*(1.f/128.f) + 1e-5f);
  u32 gg = *(const u32*)(pb + O_lng + 2*lane);
  u32 bb = *(const u32*)(pb + O_lnb + 2*lane);
  *(u32*)(xn + (size_t)n*HH + 2*lane) = pk(d0*rs*blo(gg)+blo(bb), d1*rs*bhi(gg)+bhi(bb));
}

// ---------------- qkv = xn @ [Wq|Wk|Wv]^T + b ----------------
__global__ __launch_bounds__(256) void k_gemm_qkv(const u16* __restrict__ xn,
    const u16* __restrict__ pb, u16* __restrict__ qkv){
  int wid = threadIdx.x>>6, lane = threadIdx.x & 63;
  int ct = blockIdx.y*4 + wid;          // 0..23
  int r0 = blockIdx.x*16;
  unsigned wo, bo_;
  if (ct < 8)      { wo = O_Wq; bo_ = O_bq; }
  else if (ct <16) { wo = O_Wk; bo_ = O_bk; }
  else             { wo = O_Wv; bo_ = O_bv; }
  int c0 = (ct & 7)*16;
  f32x4 acc = {0,0,0,0};
  acc = mm16<4>(xn + (size_t)r0*HH, HH, pb + wo + c0*HH, HH, acc);
  int col = ct*16 + (lane & 15);
  float bb = b2f(pb[bo_ + c0 + (lane&15)]);
#pragma unroll
  for (int j=0;j<4;++j){
    int r = r0 + ((lane>>4)<<2) + j;
    qkv[(size_t)r*384 + col] = f2b(acc[j] + bb);
  }
}

// ---------------- DIRECT vec path: vdot, vec3, Y via scalar dots (no MFMA) ----------------
__global__ __launch_bounds__(128) void k_vdir(const float* __restrict__ vecf,
    const u16* __restrict__ pb,
    u16* __restrict__ vec3, u16* __restrict__ Y, float* __restrict__ vdf){
  __shared__ float vs[3][128];
  int n = blockIdx.x, h = threadIdx.x;
#pragma unroll
  for (int c=0;c<3;++c) vs[c][h] = vecf[((size_t)n*3+c)*HH + h];
  __syncthreads();
  const u16* W1   = pb + O_Wvec + (size_t)h*HH;
  const u16* W2   = W1 + 128*HH;
  const u16* W3   = W1 + 256*HH;
  const u16* Wsrc = pb + O_Wwsrc + (size_t)h*HH;
  const u16* Wtrg = pb + O_Wwtrg + (size_t)h*HH;
  float vd = 0.f;
#pragma unroll
  for (int c=0;c<3;++c){
    float s1=0.f,s2=0.f,s3=0.f,ss=0.f,st=0.f;
    for (int k=0;k<128;++k){
      float v = vs[c][k];
      s1 += v*b2f(W1[k]);  s2 += v*b2f(W2[k]);  s3 += v*b2f(W3[k]);
      ss += v*b2f(Wsrc[k]); st += v*b2f(Wtrg[k]);
    }
    vd += s1*s2;
    size_t rr = (size_t)n*3 + c;
    vec3[rr*HH + h]     = f2b(s3);
    Y[rr*256 + h]       = f2b(ss);
    Y[rr*256 + 128 + h] = f2b(st);
  }
  vdf[(size_t)n*HH + h] = vd;
}

// ---------------- edge kernel 1: f_ij->LDS, dk/dv/ff GEMM + attn + vmsg + df(f32) ----------------
__global__ __launch_bounds__(256) void k_edge1(const float* __restrict__ f_ij,
    const u16* __restrict__ pb,
    const u16* __restrict__ qkv, const u16* __restrict__ Y,
    const int* __restrict__ ei, const float* __restrict__ r_ij, const float* __restrict__ d_ij,
    u16* __restrict__ vmsg, float* __restrict__ df){
  __shared__ u16 fs[64*128];    // f_ij tile bf16; reused for ff after GEMMs
  __shared__ u16 g2s[64*256];   // dk | dv
  int tid = threadIdx.x;
  int wid = tid>>6, lane = tid & 63;
  int e0 = blockIdx.x*64;
  {
    const float* srcA = f_ij + (size_t)e0*HH;
    for (int i = tid*4; i < 8192; i += 1024){
      f32x4 v = *(const f32x4*)(srcA + i);
      u32x2 o; o[0] = pk(v[0], v[1]); o[1] = pk(v[2], v[3]);
      *(u32x2*)(fs + i) = o;
    }
  }
  __syncthreads();
  const u16* A = fs + wid*16*HH;          // wave-local 16 rows
  for (int ct=0; ct<16; ++ct){            // dk (0..7), dv (8..15) -> g2s
    unsigned wo  = (ct<8) ? O_Wdk : O_Wdv;
    unsigned bo_ = (ct<8) ? O_bdk : O_bdv;
    int c0 = (ct&7)*16;
    f32x4 acc = {0,0,0,0};
    acc = mm16<4>(A, HH, pb + wo + c0*HH, HH, acc);
    float bb = b2f(pb[bo_ + c0 + (lane&15)]);
#pragma unroll
    for (int j=0;j<4;++j){
      int r = wid*16 + ((lane>>4)<<2) + j;
      g2s[r*256 + ct*16 + (lane&15)] = f2b(siluf(acc[j] + bb));
    }
  }
  f32x4 ffa[8];
#pragma unroll
  for (int cf=0; cf<8; ++cf){             // ff kept in registers (A still in fs)
    f32x4 acc = {0,0,0,0};
    ffa[cf] = mm16<4>(A, HH, pb + O_Wf + cf*16*HH, HH, acc);
  }
  __syncthreads();
#pragma unroll
  for (int cf=0; cf<8; ++cf){             // overwrite own fs rows with silu(ff)
    float bb = b2f(pb[O_bf + cf*16 + (lane&15)]);
#pragma unroll
    for (int j=0;j<4;++j){
      int r = wid*16 + ((lane>>4)<<2) + j;
      fs[r*HH + cf*16 + (lane&15)] = f2b(siluf(ffa[cf][j] + bb));
    }
  }
  __syncthreads();
  int h0 = 2*lane;
  for (int i=0;i<16;++i){
    int el = wid*16 + i;
    int e = e0 + el;
    int src = ei[e], dst = ei[NE + e];
    u32 qq = *(const u32*)(qkv + (size_t)dst*384 + h0);
    u32 kk = *(const u32*)(qkv + (size_t)src*384 + 128 + h0);
    u32 vv = *(const u32*)(qkv + (size_t)src*384 + 256 + h0);
    u32 dk = *(const u32*)(g2s + el*256 + h0);
    u32 dv = *(const u32*)(g2s + el*256 + 128 + h0);
    u32 ff = *(const u32*)(fs  + el*128 + h0);
    float p = blo(qq)*blo(kk)*blo(dk) + bhi(qq)*bhi(kk)*bhi(dk);
    p += __shfl_xor(p,1); p += __shfl_xor(p,2); p += __shfl_xor(p,4);   // per-head sum
    float r = r_ij[e];
    float cut = 0.5f*(__cosf(0.6283185307f*r)+1.f) * (r < 5.f ? 1.f : 0.f);
    float attn = siluf(p)*cut;
    float m0 = blo(vv)*blo(dv)*attn, m1 = bhi(vv)*bhi(dv)*attn;
    // w_dot = a.b - (a.d)(b.d)(2 - d.d);  a = Ytrg[dst], b = Ysrc[src]
    float ab0=0,ab1=0, ad0=0,ad1=0, bd0=0,bd1=0, ss=0;
#pragma unroll
    for (int c=0;c<3;++c){
      u32 aa  = *(const u32*)(Y + ((size_t)dst*3+c)*256 + 128 + h0);
      u32 bv2 = *(const u32*)(Y + ((size_t)src*3+c)*256 + h0);
      float dc = d_ij[e*3+c];
      ab0 += blo(aa)*blo(bv2); ab1 += bhi(aa)*bhi(bv2);
      ad0 += blo(aa)*dc;       ad1 += bhi(aa)*dc;
      bd0 += blo(bv2)*dc;      bd1 += bhi(bv2)*dc;
      ss  += dc*dc;
    }
    float t = 2.f - ss;
    f32x2 dfo; dfo[0] = blo(ff)*(ab0 - ad0*bd0*t); dfo[1] = bhi(ff)*(ab1 - ad1*bd1*t);
    *(f32x2*)(df + (size_t)e*HH + h0) = dfo;          // f32 OUTPUT
    *(u32*)(vmsg + (size_t)e*HH + h0) = pk(m0, m1);
  }
}

// ---------------- edge kernel 2: s GEMM + Wagg GEMM + gated + scatter ----------------
__global__ __launch_bounds__(256) void k_edge2(const u16* __restrict__ vmsg,
    const u16* __restrict__ pb,
    const float* __restrict__ vecf, const float* __restrict__ d_ij,
    const int* __restrict__ ei, const float* __restrict__ aggf,
    float* __restrict__ xacc, float* __restrict__ vacc){
  __shared__ u16 s_s[64*256];
  __shared__ u16 ex_s[128*128];
  int wid = threadIdx.x>>6, lane = threadIdx.x & 63;
  int e0 = blockIdx.x*64;
  {  // s = silu(vmsg @ Ws^T + bs)
    const u16* A = vmsg + (size_t)(e0 + wid*16)*HH;
    for (int ct=0; ct<16; ++ct){
      f32x4 acc = {0,0,0,0};
      acc = mm16<4>(A, HH, pb + O_Ws + ct*16*HH, HH, acc);
      float bb = b2f(pb[O_bs + ct*16 + (lane&15)]);
#pragma unroll
      for (int j=0;j<4;++j){
        int r = wid*16 + ((lane>>4)<<2) + j;
        s_s[r*256 + ct*16 + (lane&15)] = f2b(siluf(acc[j] + bb));
      }
    }
  }
  {  // ex = clip(e2 @ Wagg^T, 0, 1), rows = [2E,64] view of vmsg
    for (int rt = wid; rt < 8; rt += 4){
      const u16* A = vmsg + ((size_t)2*e0 + rt*16)*64;
      for (int ct=0; ct<8; ++ct){
        f32x4 acc = {0,0,0,0};
        acc = mm16<2>(A, 64, pb + O_Wagg + ct*16*64, 64, acc);
#pragma unroll
        for (int j=0;j<4;++j){
          int r = rt*16 + ((lane>>4)<<2) + j;
          ex_s[r*128 + ct*16 + (lane&15)] = f2b(fminf(fmaxf(acc[j],0.f),1.f));
        }
      }
    }
  }
  __syncthreads();
  float absA = fabsf(aggf[0]);
  int h0 = 2*lane;
  for (int i=0;i<16;++i){
    int el = wid*16 + i;
    int e = e0 + el;
    int src = ei[e], dst = ei[NE + e];
    u32 mm = *(const u32*)(vmsg + (size_t)e*HH + h0);
    u32 ml = *(const u32*)(vmsg + (size_t)e*HH + (h0 & 63));
    u32 mh = *(const u32*)(vmsg + (size_t)e*HH + 64 + (h0 & 63));
    u32 ex0 = *(const u32*)(ex_s + (2*el)*128 + h0);
    u32 ex1 = *(const u32*)(ex_s + (2*el+1)*128 + h0);
    float g0 = blo(ml)*blo(ex0) + blo(mh)*blo(ex1);
    float g1 = bhi(ml)*bhi(ex0) + bhi(mh)*bhi(ex1);
    atomicAdd(&xacc[(size_t)dst*HH + h0],     blo(mm) + absA*g0);
    atomicAdd(&xacc[(size_t)dst*HH + h0 + 1], bhi(mm) + absA*g1);
    u32 s1 = *(const u32*)(s_s + el*256 + h0);
    u32 s2 = *(const u32*)(s_s + el*256 + 128 + h0);
#pragma unroll
    for (int c=0;c<3;++c){
      f32x2 vv = *(const f32x2*)(vecf + ((size_t)src*3+c)*HH + h0);
      float dc = d_ij[e*3+c];
      atomicAdd(&vacc[((size_t)dst*3+c)*HH + h0],     vv[0]*blo(s1) + blo(s2)*dc);
      atomicAdd(&vacc[((size_t)dst*3+c)*HH + h0 + 1], vv[1]*bhi(s1) + bhi(s2)*dc);
    }
  }
}

// ---------------- update: o1/o2/o3 via scalar dots; dx, dvec (f32 OUTPUT) ----------------
__global__ __launch_bounds__(256) void k_update(const float* xacc,
    const u16* pb, const float* vdf, const u16* vec3, const float* vacc,
    float* dx, float* dvec){
  int wid = threadIdx.x>>6, lane = threadIdx.x & 63;
  int ct = blockIdx.y*4 + wid;   // 0..7
  int r0 = blockIdx.x*16;
  int h = ct*16 + (lane & 15);
  const u16* W1 = pb + O_Wo + (size_t)h*HH;
  const u16* W2 = W1 + 128*HH;
  const u16* W3 = W1 + 256*HH;
  float bo1 = b2f(pb[O_bo + h]), bo2 = b2f(pb[O_bo + 128 + h]), bo3 = b2f(pb[O_bo + 256 + h]);
#pragma unroll
  for (int j=0;j<4;++j){
    int r = r0 + ((lane>>4)<<2) + j;
    const float* xr = xacc + (size_t)r*HH;
    float s1=0.f, s2=0.f, s3=0.f;
    for (int k=0;k<128;++k){
      float xv = xr[k];
      s1 += xv*b2f(W1[k]); s2 += xv*b2f(W2[k]); s3 += xv*b2f(W3[k]);
    }
    float o1 = s1+bo1, o2 = s2+bo2, o3 = s3+bo3;
    float vdot = vdf[(size_t)r*HH + h];
    dx[(size_t)r*HH + h] = vdot*o2 + o3;
#pragma unroll
    for (int c=0;c<3;++c){
      size_t idx = ((size_t)r*3+c)*HH + h;
      dvec[idx] = b2f(vec3[idx])*o1 + vacc[idx];
    }
  }
}

extern "C" void kernel_launch(void* const* d_in, const int* in_sizes, int n_in,
                              void* d_out, int out_size, void* d_ws, size_t ws_size,
                              hipStream_t stream){
  (void)in_sizes; (void)n_in; (void)out_size; (void)ws_size;
  const float* x     = (const float*)d_in[0];
  const float* vecf  = (const float*)d_in[1];
  const int*   ei    = (const int*)d_in[2];
  const float* r_ij  = (const float*)d_in[3];
  const float* f_ij  = (const float*)d_in[4];
  const float* d_ij  = (const float*)d_in[5];
  const float* aggf  = (const float*)d_in[28];

  char* ws = (char*)d_ws;
  u16*   wsu   = (u16*)d_ws;
  u16*   vmsg  = (u16*)(ws + 0);            // [E,128] bf16
  u16*   Ybuf  = (u16*)(ws + 33554432);     // [3N,256] bf16 -> vacc f32 after edge1
  float* vacc  = (float*)(ws + 33554432);
  u16*   xn    = (u16*)(ws + 58720256);     // [N,128] bf16 -> xacc f32 after edge1
  float* xacc  = (float*)(ws + 58720256);
  u16*   vec3  = (u16*)(ws + 67108864);     // [3N,128] bf16
  u16*   qkv   = (u16*)(ws + 79691776);     // [N,384] bf16
  float* vdf   = (float*)(ws + 92274688);   // [N,128] f32

  float* out  = (float*)d_out;              // f32 OUTPUTS
  float* dx   = out;
  float* dvec = out + (size_t)NN*128;
  float* df   = out + (size_t)NN*512;

  Pack p; int c = 0;
  auto add = [&](int idx, unsigned off, unsigned n){ p.d[c].s=(const float*)d_in[idx]; p.d[c].off=off; p.d[c].n=n; ++c; };
  add(8,  O_Wq,   16384); add(10, O_Wk,   16384); add(12, O_Wv,   16384);
  add(14, O_Wdk,  16384); add(16, O_Wdv,  16384); add(23, O_Wf,   16384);
  add(25, O_Wwsrc,16384); add(26, O_Wwtrg,16384);
  add(18, O_Wvec, 49152); add(19, O_Ws,   32768); add(21, O_Wo,   49152);
  add(27, O_Wagg,  8192);
  add(9,  O_bq, 128); add(11, O_bk, 128); add(13, O_bv, 128); add(15, O_bdk, 128);
  add(17, O_bdv, 128); add(20, O_bs, 256); add(22, O_bo, 384); add(24, O_bf, 128);
  add(6,  O_lng, 128); add(7,  O_lnb, 128); add(28, O_agg, 1);
  p.cnt = c;

  k_cvt<<<dim3(128), 256, 0, stream>>>(p, wsu);
  k_ln<<<dim3(NN/4), 256, 0, stream>>>(x, wsu, xn);
  k_gemm_qkv<<<dim3(NN/16, 6), 256, 0, stream>>>(xn, wsu, qkv);
  k_vdir<<<dim3(NN), 128, 0, stream>>>(vecf, wsu, vec3, Ybuf, vdf);
  k_edge1<<<dim3(NE/64), 256, 0, stream>>>(f_ij, wsu, qkv, Ybuf, ei, r_ij, d_ij, vmsg, df);
  hipMemsetAsync(ws + 33554432, 0, 33554432, stream);   // zero vacc+xacc (Y,xn dead)
  k_edge2<<<dim3(NE/64), 256, 0, stream>>>(vmsg, wsu, vecf, d_ij, ei, aggf, xacc, vacc);
  k_update<<<dim3(NN/16, 2), 256, 0, stream>>>(xacc, wsu, vdf, vec3, vacc, dx, dvec);
}

// Round 8
// 777.593 us; speedup vs baseline: 5.2633x; 5.2633x over previous
//
#include <hip/hip_runtime.h>

#define NN 16384
#define NE 131072
#define HH 128

typedef unsigned short u16;
typedef unsigned int u32;
typedef __attribute__((ext_vector_type(8))) short short8;
typedef __attribute__((ext_vector_type(4))) float f32x4;
typedef __attribute__((ext_vector_type(2))) float f32x2;
typedef __attribute__((ext_vector_type(2))) u32 u32x2;

__device__ __forceinline__ float b2f(u16 u){ u32 i=((u32)u)<<16; float f; __builtin_memcpy(&f,&i,4); return f; }
__device__ __forceinline__ u16 f2b(float f){ u32 i; __builtin_memcpy(&i,&f,4); u32 r=(i+0x7fffu+((i>>16)&1u))>>16; return (u16)r; }
__device__ __forceinline__ float blo(u32 v){ return b2f((u16)(v&0xffffu)); }
__device__ __forceinline__ float bhi(u32 v){ return b2f((u16)(v>>16)); }
__device__ __forceinline__ u32 pk(float a, float b){ return (u32)f2b(a) | ((u32)f2b(b)<<16); }
__device__ __forceinline__ float siluf(float x){ return x/(1.f+__expf(-x)); }

// ws byte layout (total ~118.0 MB):
//   0          : vmsg [E,128] bf16 (32MB, edge1->edge2)
//   33554432   : Y [3N,256] bf16 (dead after edge1) -> vacc f32 [3N,128] (memset after edge1)
//   58720256   : xn [N,128] bf16 (dead after qkv)   -> xacc f32 [N,128]  (memset after edge1)
//   67108864   : vec3 [3N,128] bf16 (until update)
//   79691776   : qkv [N,384] bf16 (until edge1)
//   92274688   : v12 [3N,256] bf16 = vec1|vec2 (until update)
//   117440512  : params bf16 (~545KB)
#define PBASE 58720256u   // u16 units = byte 117,440,512
enum : unsigned {
  O_Wq=PBASE+0, O_Wk=PBASE+16384, O_Wv=PBASE+32768, O_Wdk=PBASE+49152,
  O_Wdv=PBASE+65536, O_Wf=PBASE+81920, O_Wwsrc=PBASE+98304, O_Wwtrg=PBASE+114688,
  O_Wvec=PBASE+131072, O_Ws=PBASE+180224, O_Wo=PBASE+212992, O_Wagg=PBASE+262144,
  O_bq=PBASE+270336, O_bk=PBASE+270464, O_bv=PBASE+270592, O_bdk=PBASE+270720,
  O_bdv=PBASE+270848, O_bs=PBASE+270976, O_bo=PBASE+271232, O_bf=PBASE+271616,
  O_lng=PBASE+271744, O_lnb=PBASE+271872, O_agg=PBASE+272000
};

struct Seg { const float* s; u32 off; u32 n; };
struct Pack { Seg d[25]; int cnt; };

// ---------------- f32 -> bf16 conversion (params only) ----------------
__global__ __launch_bounds__(256) void k_cvt(Pack p, u16* __restrict__ base){
  int tid = blockIdx.x*blockDim.x + threadIdx.x;
  int stride = gridDim.x*blockDim.x;
  for (int s=0; s<p.cnt; ++s){
    const float* src = p.d[s].s;
    u16* dst = base + p.d[s].off;
    int n = (int)p.d[s].n, n4 = n>>2;
    const f32x4* s4 = (const f32x4*)src;
    for (int i=tid; i<n4; i+=stride){
      f32x4 v = s4[i];
      u32x2 o; o[0] = pk(v[0], v[1]); o[1] = pk(v[2], v[3]);
      *(u32x2*)(dst + 4*(size_t)i) = o;
    }
    for (int i = n4*4 + tid; i < n; i += stride) dst[i] = f2b(src[i]);
  }
}

// one 16x16 output tile: C[r,c] = sum_k A[r,k]*W[c,k]; A,W bf16 row-major.
template<int NK>
__device__ __forceinline__ f32x4 mm16(const u16* A, int lda, const u16* W, int ldw, f32x4 acc){
  int lane = threadIdx.x & 63;
  const u16* pa = A + (lane & 15)*lda + ((lane>>4)<<3);
  const u16* pw = W + (lane & 15)*ldw + ((lane>>4)<<3);
#pragma unroll
  for (int kc = 0; kc < NK; ++kc){
    short8 a = *(const short8*)(pa + kc*32);
    short8 b = *(const short8*)(pw + kc*32);
    acc = __builtin_amdgcn_mfma_f32_16x16x32_bf16(a, b, acc, 0, 0, 0);
  }
  return acc;
}

// ---------------- LayerNorm (f32 in -> bf16 out) ----------------
__global__ __launch_bounds__(256) void k_ln(const float* __restrict__ x, const u16* __restrict__ pb,
                                            u16* __restrict__ xn){
  int wid = threadIdx.x>>6, lane = threadIdx.x & 63;
  int n = blockIdx.x*4 + wid;
  f32x2 v = *(const f32x2*)(x + (size_t)n*HH + 2*lane);
  float a0 = v[0], a1 = v[1];
  float s = a0 + a1;
#pragma unroll
  for (int m=32; m; m>>=1) s += __shfl_xor(s, m);
  float mu = s*(1.f/128.f);
  float d0 = a0-mu, d1 = a1-mu;
  float vs = d0*d0 + d1*d1;
#pragma unroll
  for (int m=32; m; m>>=1) vs += __shfl_xor(vs, m);
  float rs = rsqrtf(vs*(1.f/128.f) + 1e-5f);
  u32 gg = *(const u32*)(pb + O_lng + 2*lane);
  u32 bb = *(const u32*)(pb + O_lnb + 2*lane);
  *(u32*)(xn + (size_t)n*HH + 2*lane) = pk(d0*rs*blo(gg)+blo(bb), d1*rs*bhi(gg)+bhi(bb));
}

// ---------------- qkv = xn @ [Wq|Wk|Wv]^T + b ----------------
__global__ __launch_bounds__(256) void k_gemm_qkv(const u16* __restrict__ xn,
    const u16* __restrict__ pb, u16* __restrict__ qkv){
  int wid = threadIdx.x>>6, lane = threadIdx.x & 63;
  int ct = blockIdx.y*4 + wid;          // 0..23
  int r0 = blockIdx.x*16;
  unsigned wo, bo_;
  if (ct < 8)      { wo = O_Wq; bo_ = O_bq; }
  else if (ct <16) { wo = O_Wk; bo_ = O_bk; }
  else             { wo = O_Wv; bo_ = O_bv; }
  int c0 = (ct & 7)*16;
  f32x4 acc = {0,0,0,0};
  acc = mm16<4>(xn + (size_t)r0*HH, HH, pb + wo + c0*HH, HH, acc);
  int col = ct*16 + (lane & 15);
  float bb = b2f(pb[bo_ + c0 + (lane&15)]);
#pragma unroll
  for (int j=0;j<4;++j){
    int r = r0 + ((lane>>4)<<2) + j;
    qkv[(size_t)r*384 + col] = f2b(acc[j] + bb);
  }
}

// ---------------- vec GEMMs: stage 16 rows of vec (f32->bf16 LDS), all 40 col-tiles ----------------
__global__ __launch_bounds__(256) void k_gemm_vec(const float* __restrict__ vecf,
    const u16* __restrict__ pb,
    u16* __restrict__ v12, u16* __restrict__ vec3, u16* __restrict__ Y){
  __shared__ u16 At[16*128];
  int tid = threadIdx.x, wid = tid>>6, lane = tid & 63;
  int r0 = blockIdx.x*16;               // rows in [3N]
  {
    const float* src = vecf + (size_t)r0*HH;
    for (int i = tid*4; i < 2048; i += 1024){
      f32x4 v = *(const f32x4*)(src + i);
      u32x2 o; o[0] = pk(v[0], v[1]); o[1] = pk(v[2], v[3]);
      *(u32x2*)(At + i) = o;
    }
  }
  __syncthreads();
  for (int ct = wid; ct < 40; ct += 4){
    unsigned wo; int wc0;
    if (ct < 24)      { wo = O_Wvec;  wc0 = ct*16; }
    else if (ct < 32) { wo = O_Wwsrc; wc0 = (ct-24)*16; }
    else              { wo = O_Wwtrg; wc0 = (ct-32)*16; }
    f32x4 acc = {0,0,0,0};
    acc = mm16<4>(At, HH, pb + wo + wc0*HH, HH, acc);
    u16* dst; int ldc, dc0;
    if (ct < 16)      { dst = v12;  ldc = 256; dc0 = ct*16; }           // vec1|vec2
    else if (ct < 24) { dst = vec3; ldc = 128; dc0 = (ct-16)*16; }      // vec3
    else if (ct < 32) { dst = Y;    ldc = 256; dc0 = (ct-24)*16; }      // Ysrc
    else              { dst = Y;    ldc = 256; dc0 = (ct-32)*16 + 128; }// Ytrg
    int col = dc0 + (lane & 15);
#pragma unroll
    for (int j=0;j<4;++j){
      int r = r0 + ((lane>>4)<<2) + j;
      dst[(size_t)r*ldc + col] = f2b(acc[j]);
    }
  }
}

// ---------------- edge kernel 1: f_ij->LDS, dk/dv/ff GEMM + attn + vmsg + df(f32) ----------------
__global__ __launch_bounds__(256) void k_edge1(const float* __restrict__ f_ij,
    const u16* __restrict__ pb,
    const u16* __restrict__ qkv, const u16* __restrict__ Y,
    const int* __restrict__ ei, const float* __restrict__ r_ij, const float* __restrict__ d_ij,
    u16* __restrict__ vmsg, float* __restrict__ df){
  __shared__ u16 fs[64*128];    // f_ij tile bf16; reused for ff after GEMMs
  __shared__ u16 g2s[64*256];   // dk | dv
  int tid = threadIdx.x;
  int wid = tid>>6, lane = tid & 63;
  int e0 = blockIdx.x*64;
  {
    const float* srcA = f_ij + (size_t)e0*HH;
    for (int i = tid*4; i < 8192; i += 1024){
      f32x4 v = *(const f32x4*)(srcA + i);
      u32x2 o; o[0] = pk(v[0], v[1]); o[1] = pk(v[2], v[3]);
      *(u32x2*)(fs + i) = o;
    }
  }
  __syncthreads();
  const u16* A = fs + wid*16*HH;          // wave-local 16 rows
  for (int ct=0; ct<16; ++ct){            // dk (0..7), dv (8..15) -> g2s
    unsigned wo  = (ct<8) ? O_Wdk : O_Wdv;
    unsigned bo_ = (ct<8) ? O_bdk : O_bdv;
    int c0 = (ct&7)*16;
    f32x4 acc = {0,0,0,0};
    acc = mm16<4>(A, HH, pb + wo + c0*HH, HH, acc);
    float bb = b2f(pb[bo_ + c0 + (lane&15)]);
#pragma unroll
    for (int j=0;j<4;++j){
      int r = wid*16 + ((lane>>4)<<2) + j;
      g2s[r*256 + ct*16 + (lane&15)] = f2b(siluf(acc[j] + bb));
    }
  }
  f32x4 ffa[8];
#pragma unroll
  for (int cf=0; cf<8; ++cf){             // ff kept in registers (A still in fs)
    f32x4 acc = {0,0,0,0};
    ffa[cf] = mm16<4>(A, HH, pb + O_Wf + cf*16*HH, HH, acc);
  }
  __syncthreads();
#pragma unroll
  for (int cf=0; cf<8; ++cf){             // overwrite own fs rows with silu(ff)
    float bb = b2f(pb[O_bf + cf*16 + (lane&15)]);
#pragma unroll
    for (int j=0;j<4;++j){
      int r = wid*16 + ((lane>>4)<<2) + j;
      fs[r*HH + cf*16 + (lane&15)] = f2b(siluf(ffa[cf][j] + bb));
    }
  }
  __syncthreads();
  int h0 = 2*lane;
  for (int i=0;i<16;++i){
    int el = wid*16 + i;
    int e = e0 + el;
    int src = ei[e], dst = ei[NE + e];
    u32 qq = *(const u32*)(qkv + (size_t)dst*384 + h0);
    u32 kk = *(const u32*)(qkv + (size_t)src*384 + 128 + h0);
    u32 vv = *(const u32*)(qkv + (size_t)src*384 + 256 + h0);
    u32 dk = *(const u32*)(g2s + el*256 + h0);
    u32 dv = *(const u32*)(g2s + el*256 + 128 + h0);
    u32 ff = *(const u32*)(fs  + el*128 + h0);
    float p = blo(qq)*blo(kk)*blo(dk) + bhi(qq)*bhi(kk)*bhi(dk);
    p += __shfl_xor(p,1); p += __shfl_xor(p,2); p += __shfl_xor(p,4);   // per-head sum
    float r = r_ij[e];
    float cut = 0.5f*(__cosf(0.6283185307f*r)+1.f) * (r < 5.f ? 1.f : 0.f);
    float attn = siluf(p)*cut;
    float m0 = blo(vv)*blo(dv)*attn, m1 = bhi(vv)*bhi(dv)*attn;
    // w_dot = a.b - (a.d)(b.d)(2 - d.d);  a = Ytrg[dst], b = Ysrc[src]
    float ab0=0,ab1=0, ad0=0,ad1=0, bd0=0,bd1=0, ss=0;
#pragma unroll
    for (int c=0;c<3;++c){
      u32 aa  = *(const u32*)(Y + ((size_t)dst*3+c)*256 + 128 + h0);
      u32 bv2 = *(const u32*)(Y + ((size_t)src*3+c)*256 + h0);
      float dc = d_ij[e*3+c];
      ab0 += blo(aa)*blo(bv2); ab1 += bhi(aa)*bhi(bv2);
      ad0 += blo(aa)*dc;       ad1 += bhi(aa)*dc;
      bd0 += blo(bv2)*dc;      bd1 += bhi(bv2)*dc;
      ss  += dc*dc;
    }
    float t = 2.f - ss;
    f32x2 dfo; dfo[0] = blo(ff)*(ab0 - ad0*bd0*t); dfo[1] = bhi(ff)*(ab1 - ad1*bd1*t);
    *(f32x2*)(df + (size_t)e*HH + h0) = dfo;          // f32 OUTPUT
    *(u32*)(vmsg + (size_t)e*HH + h0) = pk(m0, m1);
  }
}

// ---------------- edge kernel 2: s GEMM + Wagg GEMM + gated + scatter ----------------
__global__ __launch_bounds__(256) void k_edge2(const u16* __restrict__ vmsg,
    const u16* __restrict__ pb,
    const float* __restrict__ vecf, const float* __restrict__ d_ij,
    const int* __restrict__ ei, const float* __restrict__ aggf,
    float* __restrict__ xacc, float* __restrict__ vacc){
  __shared__ u16 s_s[64*256];
  __shared__ u16 ex_s[128*128];
  int wid = threadIdx.x>>6, lane = threadIdx.x & 63;
  int e0 = blockIdx.x*64;
  {  // s = silu(vmsg @ Ws^T + bs)
    const u16* A = vmsg + (size_t)(e0 + wid*16)*HH;
    for (int ct=0; ct<16; ++ct){
      f32x4 acc = {0,0,0,0};
      acc = mm16<4>(A, HH, pb + O_Ws + ct*16*HH, HH, acc);
      float bb = b2f(pb[O_bs + ct*16 + (lane&15)]);
#pragma unroll
      for (int j=0;j<4;++j){
        int r = wid*16 + ((lane>>4)<<2) + j;
        s_s[r*256 + ct*16 + (lane&15)] = f2b(siluf(acc[j] + bb));
      }
    }
  }
  {  // ex = clip(e2 @ Wagg^T, 0, 1), rows = [2E,64] view of vmsg
    for (int rt = wid; rt < 8; rt += 4){
      const u16* A = vmsg + ((size_t)2*e0 + rt*16)*64;
      for (int ct=0; ct<8; ++ct){
        f32x4 acc = {0,0,0,0};
        acc = mm16<2>(A, 64, pb + O_Wagg + ct*16*64, 64, acc);
#pragma unroll
        for (int j=0;j<4;++j){
          int r = rt*16 + ((lane>>4)<<2) + j;
          ex_s[r*128 + ct*16 + (lane&15)] = f2b(fminf(fmaxf(acc[j],0.f),1.f));
        }
      }
    }
  }
  __syncthreads();
  float absA = fabsf(aggf[0]);
  int h0 = 2*lane;
  for (int i=0;i<16;++i){
    int el = wid*16 + i;
    int e = e0 + el;
    int src = ei[e], dst = ei[NE + e];
    u32 mm = *(const u32*)(vmsg + (size_t)e*HH + h0);
    u32 ml = *(const u32*)(vmsg + (size_t)e*HH + (h0 & 63));
    u32 mh = *(const u32*)(vmsg + (size_t)e*HH + 64 + (h0 & 63));
    u32 ex0 = *(const u32*)(ex_s + (2*el)*128 + h0);
    u32 ex1 = *(const u32*)(ex_s + (2*el+1)*128 + h0);
    float g0 = blo(ml)*blo(ex0) + blo(mh)*blo(ex1);
    float g1 = bhi(ml)*bhi(ex0) + bhi(mh)*bhi(ex1);
    atomicAdd(&xacc[(size_t)dst*HH + h0],     blo(mm) + absA*g0);
    atomicAdd(&xacc[(size_t)dst*HH + h0 + 1], bhi(mm) + absA*g1);
    u32 s1 = *(const u32*)(s_s + el*256 + h0);
    u32 s2 = *(const u32*)(s_s + el*256 + 128 + h0);
#pragma unroll
    for (int c=0;c<3;++c){
      f32x2 vv = *(const f32x2*)(vecf + ((size_t)src*3+c)*HH + h0);
      float dc = d_ij[e*3+c];
      atomicAdd(&vacc[((size_t)dst*3+c)*HH + h0],     vv[0]*blo(s1) + blo(s2)*dc);
      atomicAdd(&vacc[((size_t)dst*3+c)*HH + h0 + 1], vv[1]*bhi(s1) + bhi(s2)*dc);
    }
  }
}

// ---------------- update: o = x_agg @ Wo^T + bo (MFMA); vec_dot inline; f32 out ----------------
__global__ __launch_bounds__(256) void k_update(const float* __restrict__ xacc,
    const u16* __restrict__ pb, const u16* __restrict__ v12, const u16* __restrict__ vec3,
    const float* __restrict__ vacc,
    float* __restrict__ dx, float* __restrict__ dvec){
  int wid = threadIdx.x>>6, lane = threadIdx.x & 63;
  int ct = blockIdx.y*4 + wid;   // 0..7
  int r0 = blockIdx.x*16;
  int c0 = ct*16;
  f32x4 a1 = {0,0,0,0}, a2 = {0,0,0,0}, a3 = {0,0,0,0};
  const float* pa = xacc + (size_t)(r0 + (lane&15))*HH + ((lane>>4)<<3);
#pragma unroll
  for (int kc=0; kc<4; ++kc){
    f32x4 f0 = *(const f32x4*)(pa + kc*32);
    f32x4 f1 = *(const f32x4*)(pa + kc*32 + 4);
    short8 av;
    av[0]=(short)f2b(f0[0]); av[1]=(short)f2b(f0[1]); av[2]=(short)f2b(f0[2]); av[3]=(short)f2b(f0[3]);
    av[4]=(short)f2b(f1[0]); av[5]=(short)f2b(f1[1]); av[6]=(short)f2b(f1[2]); av[7]=(short)f2b(f1[3]);
    const u16* pw = pb + O_Wo + (size_t)(c0 + (lane&15))*HH + ((lane>>4)<<3) + kc*32;
    short8 b1 = *(const short8*)(pw);
    short8 b2 = *(const short8*)(pw + 128*HH);
    short8 b3 = *(const short8*)(pw + 256*HH);
    a1 = __builtin_amdgcn_mfma_f32_16x16x32_bf16(av, b1, a1, 0,0,0);
    a2 = __builtin_amdgcn_mfma_f32_16x16x32_bf16(av, b2, a2, 0,0,0);
    a3 = __builtin_amdgcn_mfma_f32_16x16x32_bf16(av, b3, a3, 0,0,0);
  }
  int h = c0 + (lane & 15);
  float bo1 = b2f(pb[O_bo + h]), bo2 = b2f(pb[O_bo + 128 + h]), bo3 = b2f(pb[O_bo + 256 + h]);
#pragma unroll
  for (int j=0;j<4;++j){
    int r = r0 + ((lane>>4)<<2) + j;
    float o1 = a1[j]+bo1, o2 = a2[j]+bo2, o3 = a3[j]+bo3;
    float vdot = 0.f;
#pragma unroll
    for (int c=0;c<3;++c){
      const u16* row = v12 + ((size_t)r*3 + c)*256;
      vdot += b2f(row[h]) * b2f(row[128 + h]);
    }
    dx[(size_t)r*HH + h] = vdot*o2 + o3;
#pragma unroll
    for (int c=0;c<3;++c){
      size_t idx = ((size_t)r*3+c)*HH + h;
      dvec[idx] = b2f(vec3[idx])*o1 + vacc[idx];
    }
  }
}

extern "C" void kernel_launch(void* const* d_in, const int* in_sizes, int n_in,
                              void* d_out, int out_size, void* d_ws, size_t ws_size,
                              hipStream_t stream){
  (void)in_sizes; (void)n_in; (void)out_size; (void)ws_size;
  const float* x     = (const float*)d_in[0];
  const float* vecf  = (const float*)d_in[1];
  const int*   ei    = (const int*)d_in[2];
  const float* r_ij  = (const float*)d_in[3];
  const float* f_ij  = (const float*)d_in[4];
  const float* d_ij  = (const float*)d_in[5];
  const float* aggf  = (const float*)d_in[28];

  char* ws = (char*)d_ws;
  u16*   wsu   = (u16*)d_ws;
  u16*   vmsg  = (u16*)(ws + 0);            // [E,128] bf16
  u16*   Ybuf  = (u16*)(ws + 33554432);     // [3N,256] bf16 -> vacc f32 after edge1
  float* vacc  = (float*)(ws + 33554432);
  u16*   xn    = (u16*)(ws + 58720256);     // [N,128] bf16 -> xacc f32 after edge1
  float* xacc  = (float*)(ws + 58720256);
  u16*   vec3  = (u16*)(ws + 67108864);     // [3N,128] bf16
  u16*   qkv   = (u16*)(ws + 79691776);     // [N,384] bf16
  u16*   v12   = (u16*)(ws + 92274688);     // [3N,256] bf16, live until update

  float* out  = (float*)d_out;              // f32 OUTPUTS
  float* dx   = out;
  float* dvec = out + (size_t)NN*128;
  float* df   = out + (size_t)NN*512;

  Pack p; int c = 0;
  auto add = [&](int idx, unsigned off, unsigned n){ p.d[c].s=(const float*)d_in[idx]; p.d[c].off=off; p.d[c].n=n; ++c; };
  add(8,  O_Wq,   16384); add(10, O_Wk,   16384); add(12, O_Wv,   16384);
  add(14, O_Wdk,  16384); add(16, O_Wdv,  16384); add(23, O_Wf,   16384);
  add(25, O_Wwsrc,16384); add(26, O_Wwtrg,16384);
  add(18, O_Wvec, 49152); add(19, O_Ws,   32768); add(21, O_Wo,   49152);
  add(27, O_Wagg,  8192);
  add(9,  O_bq, 128); add(11, O_bk, 128); add(13, O_bv, 128); add(15, O_bdk, 128);
  add(17, O_bdv, 128); add(20, O_bs, 256); add(22, O_bo, 384); add(24, O_bf, 128);
  add(6,  O_lng, 128); add(7,  O_lnb, 128); add(28, O_agg, 1);
  p.cnt = c;

  k_cvt<<<dim3(128), 256, 0, stream>>>(p, wsu);
  k_ln<<<dim3(NN/4), 256, 0, stream>>>(x, wsu, xn);
  k_gemm_qkv<<<dim3(NN/16, 6), 256, 0, stream>>>(xn, wsu, qkv);
  k_gemm_vec<<<dim3(3*NN/16), 256, 0, stream>>>(vecf, wsu, v12, vec3, Ybuf);
  k_edge1<<<dim3(NE/64), 256, 0, stream>>>(f_ij, wsu, qkv, Ybuf, ei, r_ij, d_ij, vmsg, df);
  hipMemsetAsync(ws + 33554432, 0, 33554432, stream);   // zero vacc+xacc (Y,xn dead)
  k_edge2<<<dim3(NE/64), 256, 0, stream>>>(vmsg, wsu, vecf, d_ij, ei, aggf, xacc, vacc);
  k_update<<<dim3(NN/16, 2), 256, 0, stream>>>(xacc, wsu, v12, vec3, vacc, dx, dvec);
}

// Round 9
// 499.488 us; speedup vs baseline: 8.1937x; 1.5568x over previous
//
#include <hip/hip_runtime.h>

#define NN 16384
#define NE 131072
#define HH 128

typedef unsigned short u16;
typedef unsigned int u32;
typedef __attribute__((ext_vector_type(8))) short short8;
typedef __attribute__((ext_vector_type(4))) float f32x4;
typedef __attribute__((ext_vector_type(2))) float f32x2;
typedef __attribute__((ext_vector_type(2))) u32 u32x2;

__device__ __forceinline__ float b2f(u16 u){ u32 i=((u32)u)<<16; float f; __builtin_memcpy(&f,&i,4); return f; }
__device__ __forceinline__ u16 f2b(float f){ u32 i; __builtin_memcpy(&i,&f,4); u32 r=(i+0x7fffu+((i>>16)&1u))>>16; return (u16)r; }
__device__ __forceinline__ float blo(u32 v){ return b2f((u16)(v&0xffffu)); }
__device__ __forceinline__ float bhi(u32 v){ return b2f((u16)(v>>16)); }
__device__ __forceinline__ u32 pk(float a, float b){ return (u32)f2b(a) | ((u32)f2b(b)<<16); }
__device__ __forceinline__ float siluf(float x){ return x/(1.f+__expf(-x)); }

// ws byte layout (total ~113.2 MiB):
//   0          : vmsg [E,128] bf16 (32MB, edge1->edge2)
//   33554432   : Y [3N,256] bf16 (dead after edge1) -> vacc f32 [3N,128] (memset after edge1)
//   58720256   : xn [N,128] bf16 (dead after qkv)   -> xacc f32 [N,128]  (memset after edge1)
//   67108864   : vec3 [3N,128] bf16 (until update)
//   79691776   : qkv [N,384] bf16 (until edge1)
//   92274688   : v12 [3N,256] bf16 = vec1|vec2 (until update)
//   117440512  : params bf16 (~545KB)
//   117985280  : cnt int[16384] ; 118050816 cur int[16384] ; 118116352 se int[E]
#define PBASE 58720256u   // u16 units = byte 117,440,512
enum : unsigned {
  O_Wq=PBASE+0, O_Wk=PBASE+16384, O_Wv=PBASE+32768, O_Wdk=PBASE+49152,
  O_Wdv=PBASE+65536, O_Wf=PBASE+81920, O_Wwsrc=PBASE+98304, O_Wwtrg=PBASE+114688,
  O_Wvec=PBASE+131072, O_Ws=PBASE+180224, O_Wo=PBASE+212992, O_Wagg=PBASE+262144,
  O_bq=PBASE+270336, O_bk=PBASE+270464, O_bv=PBASE+270592, O_bdk=PBASE+270720,
  O_bdv=PBASE+270848, O_bs=PBASE+270976, O_bo=PBASE+271232, O_bf=PBASE+271616,
  O_lng=PBASE+271744, O_lnb=PBASE+271872, O_agg=PBASE+272000
};
#define CNT_OFF 117985280u
#define CUR_OFF 118050816u
#define SE_OFF  118116352u

struct Seg { const float* s; u32 off; u32 n; };
struct Pack { Seg d[25]; int cnt; };

// ---------------- f32 -> bf16 conversion (params only) ----------------
__global__ __launch_bounds__(256) void k_cvt(Pack p, u16* __restrict__ base){
  int tid = blockIdx.x*blockDim.x + threadIdx.x;
  int stride = gridDim.x*blockDim.x;
  for (int s=0; s<p.cnt; ++s){
    const float* src = p.d[s].s;
    u16* dst = base + p.d[s].off;
    int n = (int)p.d[s].n, n4 = n>>2;
    const f32x4* s4 = (const f32x4*)src;
    for (int i=tid; i<n4; i+=stride){
      f32x4 v = s4[i];
      u32x2 o; o[0] = pk(v[0], v[1]); o[1] = pk(v[2], v[3]);
      *(u32x2*)(dst + 4*(size_t)i) = o;
    }
    for (int i = n4*4 + tid; i < n; i += stride) dst[i] = f2b(src[i]);
  }
}

// ---------------- edge sort by dst: histogram, scan, place ----------------
__global__ __launch_bounds__(256) void k_hist(const int* __restrict__ ei, int* __restrict__ cnt){
  int e = blockIdx.x*256 + threadIdx.x;
  atomicAdd(&cnt[ei[NE + e]], 1);
}
__global__ __launch_bounds__(1024) void k_scan(const int* __restrict__ cnt, int* __restrict__ cur){
  __shared__ int part[1024];
  int t = threadIdx.x;
  int base = t*16;
  int local[16]; int s = 0;
#pragma unroll
  for (int k=0;k<16;++k){ local[k] = cnt[base+k]; s += local[k]; }
  part[t] = s;
  __syncthreads();
  for (int d=1; d<1024; d<<=1){
    int v = (t>=d) ? part[t-d] : 0;
    __syncthreads();
    part[t] += v;
    __syncthreads();
  }
  int run = (t>0) ? part[t-1] : 0;
#pragma unroll
  for (int k=0;k<16;++k){ cur[base+k] = run; run += local[k]; }
}
__global__ __launch_bounds__(256) void k_place(const int* __restrict__ ei, int* __restrict__ cur,
                                               int* __restrict__ se){
  int e = blockIdx.x*256 + threadIdx.x;
  int p = atomicAdd(&cur[ei[NE + e]], 1);
  se[p] = e;
}

// one 16x16 output tile: C[r,c] = sum_k A[r,k]*W[c,k]; A,W bf16 row-major.
template<int NK>
__device__ __forceinline__ f32x4 mm16(const u16* A, int lda, const u16* W, int ldw, f32x4 acc){
  int lane = threadIdx.x & 63;
  const u16* pa = A + (lane & 15)*lda + ((lane>>4)<<3);
  const u16* pw = W + (lane & 15)*ldw + ((lane>>4)<<3);
#pragma unroll
  for (int kc = 0; kc < NK; ++kc){
    short8 a = *(const short8*)(pa + kc*32);
    short8 b = *(const short8*)(pw + kc*32);
    acc = __builtin_amdgcn_mfma_f32_16x16x32_bf16(a, b, acc, 0, 0, 0);
  }
  return acc;
}

// ---------------- LayerNorm (f32 in -> bf16 out) ----------------
__global__ __launch_bounds__(256) void k_ln(const float* __restrict__ x, const u16* __restrict__ pb,
                                            u16* __restrict__ xn){
  int wid = threadIdx.x>>6, lane = threadIdx.x & 63;
  int n = blockIdx.x*4 + wid;
  f32x2 v = *(const f32x2*)(x + (size_t)n*HH + 2*lane);
  float a0 = v[0], a1 = v[1];
  float s = a0 + a1;
#pragma unroll
  for (int m=32; m; m>>=1) s += __shfl_xor(s, m);
  float mu = s*(1.f/128.f);
  float d0 = a0-mu, d1 = a1-mu;
  float vs = d0*d0 + d1*d1;
#pragma unroll
  for (int m=32; m; m>>=1) vs += __shfl_xor(vs, m);
  float rs = rsqrtf(vs*(1.f/128.f) + 1e-5f);
  u32 gg = *(const u32*)(pb + O_lng + 2*lane);
  u32 bb = *(const u32*)(pb + O_lnb + 2*lane);
  *(u32*)(xn + (size_t)n*HH + 2*lane) = pk(d0*rs*blo(gg)+blo(bb), d1*rs*bhi(gg)+bhi(bb));
}

// ---------------- qkv = xn @ [Wq|Wk|Wv]^T + b ----------------
__global__ __launch_bounds__(256) void k_gemm_qkv(const u16* __restrict__ xn,
    const u16* __restrict__ pb, u16* __restrict__ qkv){
  int wid = threadIdx.x>>6, lane = threadIdx.x & 63;
  int ct = blockIdx.y*4 + wid;          // 0..23
  int r0 = blockIdx.x*16;
  unsigned wo, bo_;
  if (ct < 8)      { wo = O_Wq; bo_ = O_bq; }
  else if (ct <16) { wo = O_Wk; bo_ = O_bk; }
  else             { wo = O_Wv; bo_ = O_bv; }
  int c0 = (ct & 7)*16;
  f32x4 acc = {0,0,0,0};
  acc = mm16<4>(xn + (size_t)r0*HH, HH, pb + wo + c0*HH, HH, acc);
  int col = ct*16 + (lane & 15);
  float bb = b2f(pb[bo_ + c0 + (lane&15)]);
#pragma unroll
  for (int j=0;j<4;++j){
    int r = r0 + ((lane>>4)<<2) + j;
    qkv[(size_t)r*384 + col] = f2b(acc[j] + bb);
  }
}

// ---------------- vec GEMMs: stage 16 rows of vec (f32->bf16 LDS), all 40 col-tiles ----------------
__global__ __launch_bounds__(256) void k_gemm_vec(const float* __restrict__ vecf,
    const u16* __restrict__ pb,
    u16* __restrict__ v12, u16* __restrict__ vec3, u16* __restrict__ Y){
  __shared__ u16 At[16*128];
  int tid = threadIdx.x, wid = tid>>6, lane = tid & 63;
  int r0 = blockIdx.x*16;               // rows in [3N]
  {
    const float* src = vecf + (size_t)r0*HH;
    for (int i = tid*4; i < 2048; i += 1024){
      f32x4 v = *(const f32x4*)(src + i);
      u32x2 o; o[0] = pk(v[0], v[1]); o[1] = pk(v[2], v[3]);
      *(u32x2*)(At + i) = o;
    }
  }
  __syncthreads();
  for (int ct = wid; ct < 40; ct += 4){
    unsigned wo; int wc0;
    if (ct < 24)      { wo = O_Wvec;  wc0 = ct*16; }
    else if (ct < 32) { wo = O_Wwsrc; wc0 = (ct-24)*16; }
    else              { wo = O_Wwtrg; wc0 = (ct-32)*16; }
    f32x4 acc = {0,0,0,0};
    acc = mm16<4>(At, HH, pb + wo + wc0*HH, HH, acc);
    u16* dst; int ldc, dc0;
    if (ct < 16)      { dst = v12;  ldc = 256; dc0 = ct*16; }           // vec1|vec2
    else if (ct < 24) { dst = vec3; ldc = 128; dc0 = (ct-16)*16; }      // vec3
    else if (ct < 32) { dst = Y;    ldc = 256; dc0 = (ct-24)*16; }      // Ysrc
    else              { dst = Y;    ldc = 256; dc0 = (ct-32)*16 + 128; }// Ytrg
    int col = dc0 + (lane & 15);
#pragma unroll
    for (int j=0;j<4;++j){
      int r = r0 + ((lane>>4)<<2) + j;
      dst[(size_t)r*ldc + col] = f2b(acc[j]);
    }
  }
}

// ---------------- edge kernel 1: f_ij->LDS, dk/dv/ff GEMM + attn + vmsg + df(f32) ----------------
__global__ __launch_bounds__(256) void k_edge1(const float* __restrict__ f_ij,
    const u16* __restrict__ pb,
    const u16* __restrict__ qkv, const u16* __restrict__ Y,
    const int* __restrict__ ei, const float* __restrict__ r_ij, const float* __restrict__ d_ij,
    u16* __restrict__ vmsg, float* __restrict__ df){
  __shared__ u16 fs[64*128];    // f_ij tile bf16; reused for ff after GEMMs
  __shared__ u16 g2s[64*256];   // dk | dv
  int tid = threadIdx.x;
  int wid = tid>>6, lane = tid & 63;
  int e0 = blockIdx.x*64;
  {
    const float* srcA = f_ij + (size_t)e0*HH;
    for (int i = tid*4; i < 8192; i += 1024){
      f32x4 v = *(const f32x4*)(srcA + i);
      u32x2 o; o[0] = pk(v[0], v[1]); o[1] = pk(v[2], v[3]);
      *(u32x2*)(fs + i) = o;
    }
  }
  __syncthreads();
  const u16* A = fs + wid*16*HH;          // wave-local 16 rows
  for (int ct=0; ct<16; ++ct){            // dk (0..7), dv (8..15) -> g2s
    unsigned wo  = (ct<8) ? O_Wdk : O_Wdv;
    unsigned bo_ = (ct<8) ? O_bdk : O_bdv;
    int c0 = (ct&7)*16;
    f32x4 acc = {0,0,0,0};
    acc = mm16<4>(A, HH, pb + wo + c0*HH, HH, acc);
    float bb = b2f(pb[bo_ + c0 + (lane&15)]);
#pragma unroll
    for (int j=0;j<4;++j){
      int r = wid*16 + ((lane>>4)<<2) + j;
      g2s[r*256 + ct*16 + (lane&15)] = f2b(siluf(acc[j] + bb));
    }
  }
  f32x4 ffa[8];
#pragma unroll
  for (int cf=0; cf<8; ++cf){             // ff kept in registers (A still in fs)
    f32x4 acc = {0,0,0,0};
    ffa[cf] = mm16<4>(A, HH, pb + O_Wf + cf*16*HH, HH, acc);
  }
  __syncthreads();
#pragma unroll
  for (int cf=0; cf<8; ++cf){             // overwrite own fs rows with silu(ff)
    float bb = b2f(pb[O_bf + cf*16 + (lane&15)]);
#pragma unroll
    for (int j=0;j<4;++j){
      int r = wid*16 + ((lane>>4)<<2) + j;
      fs[r*HH + cf*16 + (lane&15)] = f2b(siluf(ffa[cf][j] + bb));
    }
  }
  __syncthreads();
  int h0 = 2*lane;
  for (int i=0;i<16;++i){
    int el = wid*16 + i;
    int e = e0 + el;
    int src = ei[e], dst = ei[NE + e];
    u32 qq = *(const u32*)(qkv + (size_t)dst*384 + h0);
    u32 kk = *(const u32*)(qkv + (size_t)src*384 + 128 + h0);
    u32 vv = *(const u32*)(qkv + (size_t)src*384 + 256 + h0);
    u32 dk = *(const u32*)(g2s + el*256 + h0);
    u32 dv = *(const u32*)(g2s + el*256 + 128 + h0);
    u32 ff = *(const u32*)(fs  + el*128 + h0);
    float p = blo(qq)*blo(kk)*blo(dk) + bhi(qq)*bhi(kk)*bhi(dk);
    p += __shfl_xor(p,1); p += __shfl_xor(p,2); p += __shfl_xor(p,4);   // per-head sum
    float r = r_ij[e];
    float cut = 0.5f*(__cosf(0.6283185307f*r)+1.f) * (r < 5.f ? 1.f : 0.f);
    float attn = siluf(p)*cut;
    float m0 = blo(vv)*blo(dv)*attn, m1 = bhi(vv)*bhi(dv)*attn;
    // w_dot = a.b - (a.d)(b.d)(2 - d.d);  a = Ytrg[dst], b = Ysrc[src]
    float ab0=0,ab1=0, ad0=0,ad1=0, bd0=0,bd1=0, ss=0;
#pragma unroll
    for (int c=0;c<3;++c){
      u32 aa  = *(const u32*)(Y + ((size_t)dst*3+c)*256 + 128 + h0);
      u32 bv2 = *(const u32*)(Y + ((size_t)src*3+c)*256 + h0);
      float dc = d_ij[e*3+c];
      ab0 += blo(aa)*blo(bv2); ab1 += bhi(aa)*bhi(bv2);
      ad0 += blo(aa)*dc;       ad1 += bhi(aa)*dc;
      bd0 += blo(bv2)*dc;      bd1 += bhi(bv2)*dc;
      ss  += dc*dc;
    }
    float t = 2.f - ss;
    f32x2 dfo; dfo[0] = blo(ff)*(ab0 - ad0*bd0*t); dfo[1] = bhi(ff)*(ab1 - ad1*bd1*t);
    *(f32x2*)(df + (size_t)e*HH + h0) = dfo;          // f32 OUTPUT
    *(u32*)(vmsg + (size_t)e*HH + h0) = pk(m0, m1);
  }
}

// ---------------- edge kernel 2 (dst-sorted tiles): s GEMM + Wagg GEMM + run-merged scatter ----------------
__global__ __launch_bounds__(256) void k_edge2(const u16* __restrict__ vmsg,
    const u16* __restrict__ pb,
    const float* __restrict__ vecf, const float* __restrict__ d_ij,
    const int* __restrict__ ei, const int* __restrict__ se, const float* __restrict__ aggf,
    float* __restrict__ xacc, float* __restrict__ vacc){
  __shared__ u16 s_s[64*256];
  __shared__ u16 ex_s[128*128];
  int wid = threadIdx.x>>6, lane = threadIdx.x & 63;
  int t0 = blockIdx.x*64;
  // wave-local sorted-edge registers: lane i<16 holds local row wid*16+i
  int ereg = 0, dreg = 0, sreg = 0;
  if (lane < 16){
    ereg = se[t0 + wid*16 + lane];
    dreg = ei[NE + ereg];
    sreg = ei[ereg];
  }
  {  // s = silu(vmsg @ Ws^T + bs); A rows gathered per-lane from sorted edges
    int ea = __shfl(ereg, lane & 15);
    const u16* pa = vmsg + (size_t)ea*HH + ((lane>>4)<<3);
    short8 a0 = *(const short8*)(pa);
    short8 a1 = *(const short8*)(pa + 32);
    short8 a2 = *(const short8*)(pa + 64);
    short8 a3 = *(const short8*)(pa + 96);
    for (int ct=0; ct<16; ++ct){
      const u16* pw = pb + O_Ws + (size_t)(ct*16 + (lane&15))*HH + ((lane>>4)<<3);
      f32x4 acc = {0,0,0,0};
      acc = __builtin_amdgcn_mfma_f32_16x16x32_bf16(a0, *(const short8*)(pw),      acc, 0,0,0);
      acc = __builtin_amdgcn_mfma_f32_16x16x32_bf16(a1, *(const short8*)(pw + 32), acc, 0,0,0);
      acc = __builtin_amdgcn_mfma_f32_16x16x32_bf16(a2, *(const short8*)(pw + 64), acc, 0,0,0);
      acc = __builtin_amdgcn_mfma_f32_16x16x32_bf16(a3, *(const short8*)(pw + 96), acc, 0,0,0);
      float bb = b2f(pb[O_bs + ct*16 + (lane&15)]);
#pragma unroll
      for (int j=0;j<4;++j){
        int r = wid*16 + ((lane>>4)<<2) + j;
        s_s[r*256 + ct*16 + (lane&15)] = f2b(siluf(acc[j] + bb));
      }
    }
  }
  {  // ex = clip(e2 @ Wagg^T, 0, 1); [2E,64] rows of this wave's own 16 edges
#pragma unroll
    for (int rr=0; rr<2; ++rr){
      int rt = wid*2 + rr;
      int ea2 = __shfl(ereg, 8*rr + ((lane&15)>>1));
      const u16* pa2 = vmsg + (size_t)ea2*HH + ((lane&15)&1)*64 + ((lane>>4)<<3);
      short8 b0 = *(const short8*)(pa2);
      short8 b1 = *(const short8*)(pa2 + 32);
      for (int ct=0; ct<8; ++ct){
        const u16* pw = pb + O_Wagg + (size_t)(ct*16 + (lane&15))*64 + ((lane>>4)<<3);
        f32x4 acc = {0,0,0,0};
        acc = __builtin_amdgcn_mfma_f32_16x16x32_bf16(b0, *(const short8*)(pw),      acc, 0,0,0);
        acc = __builtin_amdgcn_mfma_f32_16x16x32_bf16(b1, *(const short8*)(pw + 32), acc, 0,0,0);
#pragma unroll
        for (int j=0;j<4;++j){
          int r = rt*16 + ((lane>>4)<<2) + j;
          ex_s[r*128 + ct*16 + (lane&15)] = f2b(fminf(fmaxf(acc[j],0.f),1.f));
        }
      }
    }
  }
  __syncthreads();
  float absA = fabsf(aggf[0]);
  int h0 = 2*lane;
  int rdst = -1;
  float xc0=0.f, xc1=0.f;
  float vc00=0.f,vc01=0.f, vc10=0.f,vc11=0.f, vc20=0.f,vc21=0.f;
  for (int i=0;i<16;++i){
    int el = wid*16 + i;
    int e   = __shfl(ereg, i);
    int dst = __shfl(dreg, i);
    int src = __shfl(sreg, i);
    if (dst != rdst){
      if (rdst >= 0){
        atomicAdd(&xacc[(size_t)rdst*HH + h0],     xc0);
        atomicAdd(&xacc[(size_t)rdst*HH + h0 + 1], xc1);
        atomicAdd(&vacc[((size_t)rdst*3+0)*HH + h0],     vc00);
        atomicAdd(&vacc[((size_t)rdst*3+0)*HH + h0 + 1], vc01);
        atomicAdd(&vacc[((size_t)rdst*3+1)*HH + h0],     vc10);
        atomicAdd(&vacc[((size_t)rdst*3+1)*HH + h0 + 1], vc11);
        atomicAdd(&vacc[((size_t)rdst*3+2)*HH + h0],     vc20);
        atomicAdd(&vacc[((size_t)rdst*3+2)*HH + h0 + 1], vc21);
      }
      rdst = dst;
      xc0=xc1=vc00=vc01=vc10=vc11=vc20=vc21=0.f;
    }
    const u16* vr = vmsg + (size_t)e*HH;
    u32 mm = *(const u32*)(vr + h0);
    u32 ml = *(const u32*)(vr + (h0 & 63));
    u32 mh = *(const u32*)(vr + 64 + (h0 & 63));
    u32 ex0 = *(const u32*)(ex_s + (2*el)*128 + h0);
    u32 ex1 = *(const u32*)(ex_s + (2*el+1)*128 + h0);
    xc0 += blo(mm) + absA*(blo(ml)*blo(ex0) + blo(mh)*blo(ex1));
    xc1 += bhi(mm) + absA*(bhi(ml)*bhi(ex0) + bhi(mh)*bhi(ex1));
    u32 s1 = *(const u32*)(s_s + el*256 + h0);
    u32 s2 = *(const u32*)(s_s + el*256 + 128 + h0);
    f32x2 vv0 = *(const f32x2*)(vecf + ((size_t)src*3+0)*HH + h0);
    f32x2 vv1 = *(const f32x2*)(vecf + ((size_t)src*3+1)*HH + h0);
    f32x2 vv2 = *(const f32x2*)(vecf + ((size_t)src*3+2)*HH + h0);
    float dc0 = d_ij[(size_t)e*3+0], dc1 = d_ij[(size_t)e*3+1], dc2 = d_ij[(size_t)e*3+2];
    vc00 += vv0[0]*blo(s1) + blo(s2)*dc0;  vc01 += vv0[1]*bhi(s1) + bhi(s2)*dc0;
    vc10 += vv1[0]*blo(s1) + blo(s2)*dc1;  vc11 += vv1[1]*bhi(s1) + bhi(s2)*dc1;
    vc20 += vv2[0]*blo(s1) + blo(s2)*dc2;  vc21 += vv2[1]*bhi(s1) + bhi(s2)*dc2;
  }
  if (rdst >= 0){
    atomicAdd(&xacc[(size_t)rdst*HH + h0],     xc0);
    atomicAdd(&xacc[(size_t)rdst*HH + h0 + 1], xc1);
    atomicAdd(&vacc[((size_t)rdst*3+0)*HH + h0],     vc00);
    atomicAdd(&vacc[((size_t)rdst*3+0)*HH + h0 + 1], vc01);
    atomicAdd(&vacc[((size_t)rdst*3+1)*HH + h0],     vc10);
    atomicAdd(&vacc[((size_t)rdst*3+1)*HH + h0 + 1], vc11);
    atomicAdd(&vacc[((size_t)rdst*3+2)*HH + h0],     vc20);
    atomicAdd(&vacc[((size_t)rdst*3+2)*HH + h0 + 1], vc21);
  }
}

// ---------------- update: o = x_agg @ Wo^T + bo (MFMA); vec_dot inline; f32 out ----------------
__global__ __launch_bounds__(256) void k_update(const float* __restrict__ xacc,
    const u16* __restrict__ pb, const u16* __restrict__ v12, const u16* __restrict__ vec3,
    const float* __restrict__ vacc,
    float* __restrict__ dx, float* __restrict__ dvec){
  int wid = threadIdx.x>>6, lane = threadIdx.x & 63;
  int ct = blockIdx.y*4 + wid;   // 0..7
  int r0 = blockIdx.x*16;
  int c0 = ct*16;
  f32x4 a1 = {0,0,0,0}, a2 = {0,0,0,0}, a3 = {0,0,0,0};
  const float* pa = xacc + (size_t)(r0 + (lane&15))*HH + ((lane>>4)<<3);
#pragma unroll
  for (int kc=0; kc<4; ++kc){
    f32x4 f0 = *(const f32x4*)(pa + kc*32);
    f32x4 f1 = *(const f32x4*)(pa + kc*32 + 4);
    short8 av;
    av[0]=(short)f2b(f0[0]); av[1]=(short)f2b(f0[1]); av[2]=(short)f2b(f0[2]); av[3]=(short)f2b(f0[3]);
    av[4]=(short)f2b(f1[0]); av[5]=(short)f2b(f1[1]); av[6]=(short)f2b(f1[2]); av[7]=(short)f2b(f1[3]);
    const u16* pw = pb + O_Wo + (size_t)(c0 + (lane&15))*HH + ((lane>>4)<<3) + kc*32;
    short8 b1 = *(const short8*)(pw);
    short8 b2 = *(const short8*)(pw + 128*HH);
    short8 b3 = *(const short8*)(pw + 256*HH);
    a1 = __builtin_amdgcn_mfma_f32_16x16x32_bf16(av, b1, a1, 0,0,0);
    a2 = __builtin_amdgcn_mfma_f32_16x16x32_bf16(av, b2, a2, 0,0,0);
    a3 = __builtin_amdgcn_mfma_f32_16x16x32_bf16(av, b3, a3, 0,0,0);
  }
  int h = c0 + (lane & 15);
  float bo1 = b2f(pb[O_bo + h]), bo2 = b2f(pb[O_bo + 128 + h]), bo3 = b2f(pb[O_bo + 256 + h]);
#pragma unroll
  for (int j=0;j<4;++j){
    int r = r0 + ((lane>>4)<<2) + j;
    float o1 = a1[j]+bo1, o2 = a2[j]+bo2, o3 = a3[j]+bo3;
    float vdot = 0.f;
#pragma unroll
    for (int c=0;c<3;++c){
      const u16* row = v12 + ((size_t)r*3 + c)*256;
      vdot += b2f(row[h]) * b2f(row[128 + h]);
    }
    dx[(size_t)r*HH + h] = vdot*o2 + o3;
#pragma unroll
    for (int c=0;c<3;++c){
      size_t idx = ((size_t)r*3+c)*HH + h;
      dvec[idx] = b2f(vec3[idx])*o1 + vacc[idx];
    }
  }
}

extern "C" void kernel_launch(void* const* d_in, const int* in_sizes, int n_in,
                              void* d_out, int out_size, void* d_ws, size_t ws_size,
                              hipStream_t stream){
  (void)in_sizes; (void)n_in; (void)out_size; (void)ws_size;
  const float* x     = (const float*)d_in[0];
  const float* vecf  = (const float*)d_in[1];
  const int*   ei    = (const int*)d_in[2];
  const float* r_ij  = (const float*)d_in[3];
  const float* f_ij  = (const float*)d_in[4];
  const float* d_ij  = (const float*)d_in[5];
  const float* aggf  = (const float*)d_in[28];

  char* ws = (char*)d_ws;
  u16*   wsu   = (u16*)d_ws;
  u16*   vmsg  = (u16*)(ws + 0);            // [E,128] bf16
  u16*   Ybuf  = (u16*)(ws + 33554432);     // [3N,256] bf16 -> vacc f32 after edge1
  float* vacc  = (float*)(ws + 33554432);
  u16*   xn    = (u16*)(ws + 58720256);     // [N,128] bf16 -> xacc f32 after edge1
  float* xacc  = (float*)(ws + 58720256);
  u16*   vec3  = (u16*)(ws + 67108864);     // [3N,128] bf16
  u16*   qkv   = (u16*)(ws + 79691776);     // [N,384] bf16
  u16*   v12   = (u16*)(ws + 92274688);     // [3N,256] bf16, live until update
  int*   cnt   = (int*)(ws + CNT_OFF);
  int*   cur   = (int*)(ws + CUR_OFF);
  int*   se    = (int*)(ws + SE_OFF);

  float* out  = (float*)d_out;              // f32 OUTPUTS
  float* dx   = out;
  float* dvec = out + (size_t)NN*128;
  float* df   = out + (size_t)NN*512;

  Pack p; int c = 0;
  auto add = [&](int idx, unsigned off, unsigned n){ p.d[c].s=(const float*)d_in[idx]; p.d[c].off=off; p.d[c].n=n; ++c; };
  add(8,  O_Wq,   16384); add(10, O_Wk,   16384); add(12, O_Wv,   16384);
  add(14, O_Wdk,  16384); add(16, O_Wdv,  16384); add(23, O_Wf,   16384);
  add(25, O_Wwsrc,16384); add(26, O_Wwtrg,16384);
  add(18, O_Wvec, 49152); add(19, O_Ws,   32768); add(21, O_Wo,   49152);
  add(27, O_Wagg,  8192);
  add(9,  O_bq, 128); add(11, O_bk, 128); add(13, O_bv, 128); add(15, O_bdk, 128);
  add(17, O_bdv, 128); add(20, O_bs, 256); add(22, O_bo, 384); add(24, O_bf, 128);
  add(6,  O_lng, 128); add(7,  O_lnb, 128); add(28, O_agg, 1);
  p.cnt = c;

  hipMemsetAsync(ws + CNT_OFF, 0, 65536, stream);       // zero cnt
  k_hist<<<dim3(NE/256), 256, 0, stream>>>(ei, cnt);
  k_scan<<<dim3(1), 1024, 0, stream>>>(cnt, cur);
  k_place<<<dim3(NE/256), 256, 0, stream>>>(ei, cur, se);
  k_cvt<<<dim3(128), 256, 0, stream>>>(p, wsu);
  k_ln<<<dim3(NN/4), 256, 0, stream>>>(x, wsu, xn);
  k_gemm_qkv<<<dim3(NN/16, 6), 256, 0, stream>>>(xn, wsu, qkv);
  k_gemm_vec<<<dim3(3*NN/16), 256, 0, stream>>>(vecf, wsu, v12, vec3, Ybuf);
  k_edge1<<<dim3(NE/64), 256, 0, stream>>>(f_ij, wsu, qkv, Ybuf, ei, r_ij, d_ij, vmsg, df);
  hipMemsetAsync(ws + 33554432, 0, 33554432, stream);   // zero vacc+xacc (Y,xn dead)
  k_edge2<<<dim3(NE/64), 256, 0, stream>>>(vmsg, wsu, vecf, d_ij, ei, se, aggf, xacc, vacc);
  k_update<<<dim3(NN/16, 2), 256, 0, stream>>>(xacc, wsu, v12, vec3, vacc, dx, dvec);
}

// Round 10
// 428.624 us; speedup vs baseline: 9.5484x; 1.1653x over previous
//
#include <hip/hip_runtime.h>

#define NN 16384
#define NE 131072
#define HH 128

typedef unsigned short u16;
typedef unsigned int u32;
typedef __attribute__((ext_vector_type(8))) short short8;
typedef __attribute__((ext_vector_type(4))) float f32x4;
typedef __attribute__((ext_vector_type(2))) float f32x2;
typedef __attribute__((ext_vector_type(2))) u32 u32x2;

__device__ __forceinline__ float b2f(u16 u){ u32 i=((u32)u)<<16; float f; __builtin_memcpy(&f,&i,4); return f; }
__device__ __forceinline__ u16 f2b(float f){ u32 i; __builtin_memcpy(&i,&f,4); u32 r=(i+0x7fffu+((i>>16)&1u))>>16; return (u16)r; }
__device__ __forceinline__ float blo(u32 v){ return b2f((u16)(v&0xffffu)); }
__device__ __forceinline__ float bhi(u32 v){ return b2f((u16)(v>>16)); }
__device__ __forceinline__ u32 pk(float a, float b){ return (u32)f2b(a) | ((u32)f2b(b)<<16); }
__device__ __forceinline__ float siluf(float x){ return x/(1.f+__expf(-x)); }

// ws byte layout:
//   0          : xacc f32 [N,128] (8MB)
//   8388608    : vacc f32 [3N,128] (25MB) -> end 33,554,432
//   33554432   : Y [3N,256] bf16 (25MB)
//   58720256   : xn [N,128] bf16 (4MB)
//   67108864   : vec3 [3N,128] bf16 (12.6MB)
//   79691776   : qkv [N,384] bf16 (12.6MB)
//   92274688   : v12 [3N,256] bf16 (25MB) -> 117,440,512
//   117440512  : params bf16 (~545KB)
//   117985280  : cnt int[16384]; 118050816 cur; 118116352 se int[E]
#define PBASE 58720256u   // u16 units = byte 117,440,512
enum : unsigned {
  O_Wq=PBASE+0, O_Wk=PBASE+16384, O_Wv=PBASE+32768, O_Wdk=PBASE+49152,
  O_Wdv=PBASE+65536, O_Wf=PBASE+81920, O_Wwsrc=PBASE+98304, O_Wwtrg=PBASE+114688,
  O_Wvec=PBASE+131072, O_Ws=PBASE+180224, O_Wo=PBASE+212992, O_Wagg=PBASE+262144,
  O_bq=PBASE+270336, O_bk=PBASE+270464, O_bv=PBASE+270592, O_bdk=PBASE+270720,
  O_bdv=PBASE+270848, O_bs=PBASE+270976, O_bo=PBASE+271232, O_bf=PBASE+271616,
  O_lng=PBASE+271744, O_lnb=PBASE+271872, O_agg=PBASE+272000
};
#define CNT_OFF 117985280u
#define CUR_OFF 118050816u
#define SE_OFF  118116352u

struct Seg { const float* s; u32 off; u32 n; };
struct Pack { Seg d[25]; int cnt; };

// ---------------- f32 -> bf16 conversion (params only) ----------------
__global__ __launch_bounds__(256) void k_cvt(Pack p, u16* __restrict__ base){
  int tid = blockIdx.x*blockDim.x + threadIdx.x;
  int stride = gridDim.x*blockDim.x;
  for (int s=0; s<p.cnt; ++s){
    const float* src = p.d[s].s;
    u16* dst = base + p.d[s].off;
    int n = (int)p.d[s].n, n4 = n>>2;
    const f32x4* s4 = (const f32x4*)src;
    for (int i=tid; i<n4; i+=stride){
      f32x4 v = s4[i];
      u32x2 o; o[0] = pk(v[0], v[1]); o[1] = pk(v[2], v[3]);
      *(u32x2*)(dst + 4*(size_t)i) = o;
    }
    for (int i = n4*4 + tid; i < n; i += stride) dst[i] = f2b(src[i]);
  }
}

// ---------------- edge sort by dst: histogram, scan, place ----------------
__global__ __launch_bounds__(256) void k_hist(const int* __restrict__ ei, int* __restrict__ cnt){
  int e = blockIdx.x*256 + threadIdx.x;
  atomicAdd(&cnt[ei[NE + e]], 1);
}
__global__ __launch_bounds__(1024) void k_scan(const int* __restrict__ cnt, int* __restrict__ cur){
  __shared__ int part[1024];
  int t = threadIdx.x;
  int base = t*16;
  int local[16]; int s = 0;
#pragma unroll
  for (int k=0;k<16;++k){ local[k] = cnt[base+k]; s += local[k]; }
  part[t] = s;
  __syncthreads();
  for (int d=1; d<1024; d<<=1){
    int v = (t>=d) ? part[t-d] : 0;
    __syncthreads();
    part[t] += v;
    __syncthreads();
  }
  int run = (t>0) ? part[t-1] : 0;
#pragma unroll
  for (int k=0;k<16;++k){ cur[base+k] = run; run += local[k]; }
}
__global__ __launch_bounds__(256) void k_place(const int* __restrict__ ei, int* __restrict__ cur,
                                               int* __restrict__ se){
  int e = blockIdx.x*256 + threadIdx.x;
  int p = atomicAdd(&cur[ei[NE + e]], 1);
  se[p] = e;
}

// one 16x16 output tile helper (A/W bf16 row-major)
template<int NK>
__device__ __forceinline__ f32x4 mm16(const u16* A, int lda, const u16* W, int ldw, f32x4 acc){
  int lane = threadIdx.x & 63;
  const u16* pa = A + (lane & 15)*lda + ((lane>>4)<<3);
  const u16* pw = W + (lane & 15)*ldw + ((lane>>4)<<3);
#pragma unroll
  for (int kc = 0; kc < NK; ++kc){
    short8 a = *(const short8*)(pa + kc*32);
    short8 b = *(const short8*)(pw + kc*32);
    acc = __builtin_amdgcn_mfma_f32_16x16x32_bf16(a, b, acc, 0, 0, 0);
  }
  return acc;
}

// ---------------- LayerNorm (f32 in -> bf16 out) ----------------
__global__ __launch_bounds__(256) void k_ln(const float* __restrict__ x, const u16* __restrict__ pb,
                                            u16* __restrict__ xn){
  int wid = threadIdx.x>>6, lane = threadIdx.x & 63;
  int n = blockIdx.x*4 + wid;
  f32x2 v = *(const f32x2*)(x + (size_t)n*HH + 2*lane);
  float a0 = v[0], a1 = v[1];
  float s = a0 + a1;
#pragma unroll
  for (int m=32; m; m>>=1) s += __shfl_xor(s, m);
  float mu = s*(1.f/128.f);
  float d0 = a0-mu, d1 = a1-mu;
  float vs = d0*d0 + d1*d1;
#pragma unroll
  for (int m=32; m; m>>=1) vs += __shfl_xor(vs, m);
  float rs = rsqrtf(vs*(1.f/128.f) + 1e-5f);
  u32 gg = *(const u32*)(pb + O_lng + 2*lane);
  u32 bb = *(const u32*)(pb + O_lnb + 2*lane);
  *(u32*)(xn + (size_t)n*HH + 2*lane) = pk(d0*rs*blo(gg)+blo(bb), d1*rs*bhi(gg)+bhi(bb));
}

// ---------------- qkv = xn @ [Wq|Wk|Wv]^T + b ----------------
__global__ __launch_bounds__(256) void k_gemm_qkv(const u16* __restrict__ xn,
    const u16* __restrict__ pb, u16* __restrict__ qkv){
  int wid = threadIdx.x>>6, lane = threadIdx.x & 63;
  int ct = blockIdx.y*4 + wid;          // 0..23
  int r0 = blockIdx.x*16;
  unsigned wo, bo_;
  if (ct < 8)      { wo = O_Wq; bo_ = O_bq; }
  else if (ct <16) { wo = O_Wk; bo_ = O_bk; }
  else             { wo = O_Wv; bo_ = O_bv; }
  int c0 = (ct & 7)*16;
  f32x4 acc = {0,0,0,0};
  acc = mm16<4>(xn + (size_t)r0*HH, HH, pb + wo + c0*HH, HH, acc);
  int col = ct*16 + (lane & 15);
  float bb = b2f(pb[bo_ + c0 + (lane&15)]);
#pragma unroll
  for (int j=0;j<4;++j){
    int r = r0 + ((lane>>4)<<2) + j;
    qkv[(size_t)r*384 + col] = f2b(acc[j] + bb);
  }
}

// ---------------- vec GEMMs: stage 16 rows of vec (f32->bf16 LDS), all 40 col-tiles ----------------
__global__ __launch_bounds__(256) void k_gemm_vec(const float* __restrict__ vecf,
    const u16* __restrict__ pb,
    u16* __restrict__ v12, u16* __restrict__ vec3, u16* __restrict__ Y){
  __shared__ u16 At[16*128];
  int tid = threadIdx.x, wid = tid>>6, lane = tid & 63;
  int r0 = blockIdx.x*16;               // rows in [3N]
  {
    const float* src = vecf + (size_t)r0*HH;
    for (int i = tid*4; i < 2048; i += 1024){
      f32x4 v = *(const f32x4*)(src + i);
      u32x2 o; o[0] = pk(v[0], v[1]); o[1] = pk(v[2], v[3]);
      *(u32x2*)(At + i) = o;
    }
  }
  __syncthreads();
  for (int ct = wid; ct < 40; ct += 4){
    unsigned wo; int wc0;
    if (ct < 24)      { wo = O_Wvec;  wc0 = ct*16; }
    else if (ct < 32) { wo = O_Wwsrc; wc0 = (ct-24)*16; }
    else              { wo = O_Wwtrg; wc0 = (ct-32)*16; }
    f32x4 acc = {0,0,0,0};
    acc = mm16<4>(At, HH, pb + wo + wc0*HH, HH, acc);
    u16* dst; int ldc, dc0;
    if (ct < 16)      { dst = v12;  ldc = 256; dc0 = ct*16; }           // vec1|vec2
    else if (ct < 24) { dst = vec3; ldc = 128; dc0 = (ct-16)*16; }      // vec3
    else if (ct < 32) { dst = Y;    ldc = 256; dc0 = (ct-24)*16; }      // Ysrc
    else              { dst = Y;    ldc = 256; dc0 = (ct-32)*16 + 128; }// Ytrg
    int col = dc0 + (lane & 15);
#pragma unroll
    for (int j=0;j<4;++j){
      int r = r0 + ((lane>>4)<<2) + j;
      dst[(size_t)r*ldc + col] = f2b(acc[j]);
    }
  }
}

// ---------------- FUSED edge kernel (dst-sorted, zero barriers, wave-local LDS) ----------------
// fs : f_ij tile -> silu(ff) -> vmsg          (16KB)
// g2s: dk|dv -> ex_s[128][128] -> s_s[64][256] (32KB)
__global__ __launch_bounds__(256) void k_edge(const float* __restrict__ f_ij,
    const u16* __restrict__ pb,
    const u16* __restrict__ qkv, const u16* __restrict__ Y,
    const int* __restrict__ ei, const int* __restrict__ se,
    const float* __restrict__ r_ij, const float* __restrict__ d_ij,
    const float* __restrict__ vecf, const float* __restrict__ aggf,
    float* __restrict__ df, float* __restrict__ xacc, float* __restrict__ vacc){
  __shared__ u16 fs[64*128];
  __shared__ u16 g2s[64*256];
  int tid = threadIdx.x, wid = tid>>6, lane = tid & 63;
  int t0 = blockIdx.x*64;
  int ereg=0, dreg=0, sreg=0;
  if (lane < 16){
    ereg = se[t0 + wid*16 + lane];
    dreg = ei[NE + ereg];
    sreg = ei[ereg];
  }
  // ---- stage this wave's 16 sorted f_ij rows into fs (wave-local) ----
#pragma unroll
  for (int pass=0; pass<8; ++pass){
    int idx = pass*256 + lane*4;          // f32 index within wave's 16 rows
    int rloc = idx >> 7, col = idx & 127;
    int er = __shfl(ereg, rloc);
    f32x4 v = *(const f32x4*)(f_ij + (size_t)er*HH + col);
    u32x2 o; o[0]=pk(v[0],v[1]); o[1]=pk(v[2],v[3]);
    *(u32x2*)(fs + (wid*16 + rloc)*HH + col) = o;
  }
  // ---- hoist A fragments (own rows) ----
  {
    const u16* pa = fs + (size_t)(wid*16 + (lane&15))*HH + ((lane>>4)<<3);
    short8 a0 = *(const short8*)(pa);
    short8 a1 = *(const short8*)(pa + 32);
    short8 a2 = *(const short8*)(pa + 64);
    short8 a3 = *(const short8*)(pa + 96);
    // dk (0..7), dv (8..15) -> g2s
    for (int ct=0; ct<16; ++ct){
      unsigned wo  = (ct<8) ? O_Wdk : O_Wdv;
      unsigned bo_ = (ct<8) ? O_bdk : O_bdv;
      int c0 = (ct&7)*16;
      const u16* pw = pb + wo + (size_t)(c0 + (lane&15))*HH + ((lane>>4)<<3);
      f32x4 acc = {0,0,0,0};
      acc = __builtin_amdgcn_mfma_f32_16x16x32_bf16(a0, *(const short8*)(pw),      acc, 0,0,0);
      acc = __builtin_amdgcn_mfma_f32_16x16x32_bf16(a1, *(const short8*)(pw + 32), acc, 0,0,0);
      acc = __builtin_amdgcn_mfma_f32_16x16x32_bf16(a2, *(const short8*)(pw + 64), acc, 0,0,0);
      acc = __builtin_amdgcn_mfma_f32_16x16x32_bf16(a3, *(const short8*)(pw + 96), acc, 0,0,0);
      float bb = b2f(pb[bo_ + c0 + (lane&15)]);
#pragma unroll
      for (int j=0;j<4;++j){
        int r = wid*16 + ((lane>>4)<<2) + j;
        g2s[r*256 + ct*16 + (lane&15)] = f2b(siluf(acc[j] + bb));
      }
    }
    // ff -> regs -> overwrite own fs rows with silu(ff)
    f32x4 ffa[8];
#pragma unroll
    for (int cf=0; cf<8; ++cf){
      const u16* pw = pb + O_Wf + (size_t)(cf*16 + (lane&15))*HH + ((lane>>4)<<3);
      f32x4 acc = {0,0,0,0};
      acc = __builtin_amdgcn_mfma_f32_16x16x32_bf16(a0, *(const short8*)(pw),      acc, 0,0,0);
      acc = __builtin_amdgcn_mfma_f32_16x16x32_bf16(a1, *(const short8*)(pw + 32), acc, 0,0,0);
      acc = __builtin_amdgcn_mfma_f32_16x16x32_bf16(a2, *(const short8*)(pw + 64), acc, 0,0,0);
      acc = __builtin_amdgcn_mfma_f32_16x16x32_bf16(a3, *(const short8*)(pw + 96), acc, 0,0,0);
      ffa[cf] = acc;
    }
#pragma unroll
    for (int cf=0; cf<8; ++cf){
      float bb = b2f(pb[O_bf + cf*16 + (lane&15)]);
#pragma unroll
      for (int j=0;j<4;++j){
        int r = wid*16 + ((lane>>4)<<2) + j;
        fs[r*HH + cf*16 + (lane&15)] = f2b(siluf(ffa[cf][j] + bb));
      }
    }
  }
  // ---- phase B: attn + vmsg(->fs) + df, with dst-run gather caching ----
  int h0 = 2*lane;
  {
    int pdst = -1; u32 qq=0, ya0=0, ya1=0, ya2=0;
    for (int i=0;i<16;++i){
      int el = wid*16 + i;
      int e   = __shfl(ereg, i);
      int dst = __shfl(dreg, i);
      int src = __shfl(sreg, i);
      if (dst != pdst){
        qq  = *(const u32*)(qkv + (size_t)dst*384 + h0);
        ya0 = *(const u32*)(Y + ((size_t)dst*3+0)*256 + 128 + h0);
        ya1 = *(const u32*)(Y + ((size_t)dst*3+1)*256 + 128 + h0);
        ya2 = *(const u32*)(Y + ((size_t)dst*3+2)*256 + 128 + h0);
        pdst = dst;
      }
      u32 kk = *(const u32*)(qkv + (size_t)src*384 + 128 + h0);
      u32 vv = *(const u32*)(qkv + (size_t)src*384 + 256 + h0);
      u32 dk = *(const u32*)(g2s + el*256 + h0);
      u32 dv = *(const u32*)(g2s + el*256 + 128 + h0);
      u32 ff = *(const u32*)(fs  + el*HH + h0);
      float p = blo(qq)*blo(kk)*blo(dk) + bhi(qq)*bhi(kk)*bhi(dk);
      p += __shfl_xor(p,1); p += __shfl_xor(p,2); p += __shfl_xor(p,4);
      float r = r_ij[e];
      float cut = 0.5f*(__cosf(0.6283185307f*r)+1.f) * (r < 5.f ? 1.f : 0.f);
      float attn = siluf(p)*cut;
      float m0 = blo(vv)*blo(dv)*attn, m1 = bhi(vv)*bhi(dv)*attn;
      // w_dot
      float ab0=0,ab1=0, ad0=0,ad1=0, bd0=0,bd1=0, ss=0;
      u32 ya[3] = {ya0, ya1, ya2};
#pragma unroll
      for (int c=0;c<3;++c){
        u32 bv2 = *(const u32*)(Y + ((size_t)src*3+c)*256 + h0);
        float dc = d_ij[(size_t)e*3+c];
        ab0 += blo(ya[c])*blo(bv2); ab1 += bhi(ya[c])*bhi(bv2);
        ad0 += blo(ya[c])*dc;       ad1 += bhi(ya[c])*dc;
        bd0 += blo(bv2)*dc;         bd1 += bhi(bv2)*dc;
        ss  += dc*dc;
      }
      float t = 2.f - ss;
      f32x2 dfo; dfo[0] = blo(ff)*(ab0 - ad0*bd0*t); dfo[1] = bhi(ff)*(ab1 - ad1*bd1*t);
      *(f32x2*)(df + (size_t)e*HH + h0) = dfo;
      *(u32*)(fs + el*HH + h0) = pk(m0, m1);   // vmsg into fs (ff already consumed)
    }
  }
  float absA = fabsf(aggf[0]);
  // ---- phase C1: ex GEMM (vs=fs rows) -> ex_s (over own g2s region) ----
#pragma unroll
  for (int rr=0; rr<2; ++rr){
    int rt = wid*2 + rr;
    int el2 = wid*16 + 8*rr + ((lane&15)>>1);
    const u16* pa2 = fs + (size_t)el2*HH + ((lane&15)&1)*64 + ((lane>>4)<<3);
    short8 b0 = *(const short8*)(pa2);
    short8 b1 = *(const short8*)(pa2 + 32);
    for (int ct=0; ct<8; ++ct){
      const u16* pw = pb + O_Wagg + (size_t)(ct*16 + (lane&15))*64 + ((lane>>4)<<3);
      f32x4 acc = {0,0,0,0};
      acc = __builtin_amdgcn_mfma_f32_16x16x32_bf16(b0, *(const short8*)(pw),      acc, 0,0,0);
      acc = __builtin_amdgcn_mfma_f32_16x16x32_bf16(b1, *(const short8*)(pw + 32), acc, 0,0,0);
#pragma unroll
      for (int j=0;j<4;++j){
        int r = rt*16 + ((lane>>4)<<2) + j;
        g2s[r*128 + ct*16 + (lane&15)] = f2b(fminf(fmaxf(acc[j],0.f),1.f));
      }
    }
  }
  // ---- scatter-x (run-merged): reads fs (vmsg) + g2s (ex) ----
  {
    int rdst = -1; float xc0=0.f, xc1=0.f;
    for (int i=0;i<16;++i){
      int el = wid*16 + i;
      int dst = __shfl(dreg, i);
      if (dst != rdst){
        if (rdst >= 0){
          atomicAdd(&xacc[(size_t)rdst*HH + h0],     xc0);
          atomicAdd(&xacc[(size_t)rdst*HH + h0 + 1], xc1);
        }
        rdst = dst; xc0 = xc1 = 0.f;
      }
      u32 mm = *(const u32*)(fs + el*HH + h0);
      u32 ml = *(const u32*)(fs + el*HH + (h0 & 63));
      u32 mh = *(const u32*)(fs + el*HH + 64 + (h0 & 63));
      u32 ex0 = *(const u32*)(g2s + (2*el)*128 + h0);
      u32 ex1 = *(const u32*)(g2s + (2*el+1)*128 + h0);
      xc0 += blo(mm) + absA*(blo(ml)*blo(ex0) + blo(mh)*blo(ex1));
      xc1 += bhi(mm) + absA*(bhi(ml)*bhi(ex0) + bhi(mh)*bhi(ex1));
    }
    if (rdst >= 0){
      atomicAdd(&xacc[(size_t)rdst*HH + h0],     xc0);
      atomicAdd(&xacc[(size_t)rdst*HH + h0 + 1], xc1);
    }
  }
  // ---- phase C2: s GEMM (A=fs vmsg rows) -> s_s (over own g2s region) ----
  {
    const u16* ps = fs + (size_t)(wid*16 + (lane&15))*HH + ((lane>>4)<<3);
    short8 sa0 = *(const short8*)(ps);
    short8 sa1 = *(const short8*)(ps + 32);
    short8 sa2 = *(const short8*)(ps + 64);
    short8 sa3 = *(const short8*)(ps + 96);
    for (int ct=0; ct<16; ++ct){
      const u16* pw = pb + O_Ws + (size_t)(ct*16 + (lane&15))*HH + ((lane>>4)<<3);
      f32x4 acc = {0,0,0,0};
      acc = __builtin_amdgcn_mfma_f32_16x16x32_bf16(sa0, *(const short8*)(pw),      acc, 0,0,0);
      acc = __builtin_amdgcn_mfma_f32_16x16x32_bf16(sa1, *(const short8*)(pw + 32), acc, 0,0,0);
      acc = __builtin_amdgcn_mfma_f32_16x16x32_bf16(sa2, *(const short8*)(pw + 64), acc, 0,0,0);
      acc = __builtin_amdgcn_mfma_f32_16x16x32_bf16(sa3, *(const short8*)(pw + 96), acc, 0,0,0);
      float bb = b2f(pb[O_bs + ct*16 + (lane&15)]);
#pragma unroll
      for (int j=0;j<4;++j){
        int r = wid*16 + ((lane>>4)<<2) + j;
        g2s[r*256 + ct*16 + (lane&15)] = f2b(siluf(acc[j] + bb));
      }
    }
  }
  // ---- scatter-v (run-merged): reads g2s (s1|s2) + vec gathers ----
  {
    int rdst = -1;
    float vc00=0.f,vc01=0.f, vc10=0.f,vc11=0.f, vc20=0.f,vc21=0.f;
    for (int i=0;i<16;++i){
      int el = wid*16 + i;
      int e   = __shfl(ereg, i);
      int dst = __shfl(dreg, i);
      int src = __shfl(sreg, i);
      if (dst != rdst){
        if (rdst >= 0){
          atomicAdd(&vacc[((size_t)rdst*3+0)*HH + h0],     vc00);
          atomicAdd(&vacc[((size_t)rdst*3+0)*HH + h0 + 1], vc01);
          atomicAdd(&vacc[((size_t)rdst*3+1)*HH + h0],     vc10);
          atomicAdd(&vacc[((size_t)rdst*3+1)*HH + h0 + 1], vc11);
          atomicAdd(&vacc[((size_t)rdst*3+2)*HH + h0],     vc20);
          atomicAdd(&vacc[((size_t)rdst*3+2)*HH + h0 + 1], vc21);
        }
        rdst = dst;
        vc00=vc01=vc10=vc11=vc20=vc21=0.f;
      }
      u32 s1 = *(const u32*)(g2s + el*256 + h0);
      u32 s2 = *(const u32*)(g2s + el*256 + 128 + h0);
      f32x2 vv0 = *(const f32x2*)(vecf + ((size_t)src*3+0)*HH + h0);
      f32x2 vv1 = *(const f32x2*)(vecf + ((size_t)src*3+1)*HH + h0);
      f32x2 vv2 = *(const f32x2*)(vecf + ((size_t)src*3+2)*HH + h0);
      float dc0 = d_ij[(size_t)e*3+0], dc1 = d_ij[(size_t)e*3+1], dc2 = d_ij[(size_t)e*3+2];
      vc00 += vv0[0]*blo(s1) + blo(s2)*dc0;  vc01 += vv0[1]*bhi(s1) + bhi(s2)*dc0;
      vc10 += vv1[0]*blo(s1) + blo(s2)*dc1;  vc11 += vv1[1]*bhi(s1) + bhi(s2)*dc1;
      vc20 += vv2[0]*blo(s1) + blo(s2)*dc2;  vc21 += vv2[1]*bhi(s1) + bhi(s2)*dc2;
    }
    if (rdst >= 0){
      atomicAdd(&vacc[((size_t)rdst*3+0)*HH + h0],     vc00);
      atomicAdd(&vacc[((size_t)rdst*3+0)*HH + h0 + 1], vc01);
      atomicAdd(&vacc[((size_t)rdst*3+1)*HH + h0],     vc10);
      atomicAdd(&vacc[((size_t)rdst*3+1)*HH + h0 + 1], vc11);
      atomicAdd(&vacc[((size_t)rdst*3+2)*HH + h0],     vc20);
      atomicAdd(&vacc[((size_t)rdst*3+2)*HH + h0 + 1], vc21);
    }
  }
}

// ---------------- update: o = x_agg @ Wo^T + bo (MFMA); vec_dot inline; f32 out ----------------
__global__ __launch_bounds__(256) void k_update(const float* __restrict__ xacc,
    const u16* __restrict__ pb, const u16* __restrict__ v12, const u16* __restrict__ vec3,
    const float* __restrict__ vacc,
    float* __restrict__ dx, float* __restrict__ dvec){
  int wid = threadIdx.x>>6, lane = threadIdx.x & 63;
  int ct = blockIdx.y*4 + wid;   // 0..7
  int r0 = blockIdx.x*16;
  int c0 = ct*16;
  f32x4 a1 = {0,0,0,0}, a2 = {0,0,0,0}, a3 = {0,0,0,0};
  const float* pa = xacc + (size_t)(r0 + (lane&15))*HH + ((lane>>4)<<3);
#pragma unroll
  for (int kc=0; kc<4; ++kc){
    f32x4 f0 = *(const f32x4*)(pa + kc*32);
    f32x4 f1 = *(const f32x4*)(pa + kc*32 + 4);
    short8 av;
    av[0]=(short)f2b(f0[0]); av[1]=(short)f2b(f0[1]); av[2]=(short)f2b(f0[2]); av[3]=(short)f2b(f0[3]);
    av[4]=(short)f2b(f1[0]); av[5]=(short)f2b(f1[1]); av[6]=(short)f2b(f1[2]); av[7]=(short)f2b(f1[3]);
    const u16* pw = pb + O_Wo + (size_t)(c0 + (lane&15))*HH + ((lane>>4)<<3) + kc*32;
    short8 b1 = *(const short8*)(pw);
    short8 b2 = *(const short8*)(pw + 128*HH);
    short8 b3 = *(const short8*)(pw + 256*HH);
    a1 = __builtin_amdgcn_mfma_f32_16x16x32_bf16(av, b1, a1, 0,0,0);
    a2 = __builtin_amdgcn_mfma_f32_16x16x32_bf16(av, b2, a2, 0,0,0);
    a3 = __builtin_amdgcn_mfma_f32_16x16x32_bf16(av, b3, a3, 0,0,0);
  }
  int h = c0 + (lane & 15);
  float bo1 = b2f(pb[O_bo + h]), bo2 = b2f(pb[O_bo + 128 + h]), bo3 = b2f(pb[O_bo + 256 + h]);
#pragma unroll
  for (int j=0;j<4;++j){
    int r = r0 + ((lane>>4)<<2) + j;
    float o1 = a1[j]+bo1, o2 = a2[j]+bo2, o3 = a3[j]+bo3;
    float vdot = 0.f;
#pragma unroll
    for (int c=0;c<3;++c){
      const u16* row = v12 + ((size_t)r*3 + c)*256;
      vdot += b2f(row[h]) * b2f(row[128 + h]);
    }
    dx[(size_t)r*HH + h] = vdot*o2 + o3;
#pragma unroll
    for (int c=0;c<3;++c){
      size_t idx = ((size_t)r*3+c)*HH + h;
      dvec[idx] = b2f(vec3[idx])*o1 + vacc[idx];
    }
  }
}

extern "C" void kernel_launch(void* const* d_in, const int* in_sizes, int n_in,
                              void* d_out, int out_size, void* d_ws, size_t ws_size,
                              hipStream_t stream){
  (void)in_sizes; (void)n_in; (void)out_size; (void)ws_size;
  const float* x     = (const float*)d_in[0];
  const float* vecf  = (const float*)d_in[1];
  const int*   ei    = (const int*)d_in[2];
  const float* r_ij  = (const float*)d_in[3];
  const float* f_ij  = (const float*)d_in[4];
  const float* d_ij  = (const float*)d_in[5];
  const float* aggf  = (const float*)d_in[28];

  char* ws = (char*)d_ws;
  u16*   wsu   = (u16*)d_ws;
  float* xacc  = (float*)(ws + 0);          // [N,128] f32
  float* vacc  = (float*)(ws + 8388608);    // [3N,128] f32
  u16*   Ybuf  = (u16*)(ws + 33554432);     // [3N,256] bf16
  u16*   xn    = (u16*)(ws + 58720256);     // [N,128] bf16
  u16*   vec3  = (u16*)(ws + 67108864);     // [3N,128] bf16
  u16*   qkv   = (u16*)(ws + 79691776);     // [N,384] bf16
  u16*   v12   = (u16*)(ws + 92274688);     // [3N,256] bf16
  int*   cnt   = (int*)(ws + CNT_OFF);
  int*   cur   = (int*)(ws + CUR_OFF);
  int*   se    = (int*)(ws + SE_OFF);

  float* out  = (float*)d_out;
  float* dx   = out;
  float* dvec = out + (size_t)NN*128;
  float* df   = out + (size_t)NN*512;

  Pack p; int c = 0;
  auto add = [&](int idx, unsigned off, unsigned n){ p.d[c].s=(const float*)d_in[idx]; p.d[c].off=off; p.d[c].n=n; ++c; };
  add(8,  O_Wq,   16384); add(10, O_Wk,   16384); add(12, O_Wv,   16384);
  add(14, O_Wdk,  16384); add(16, O_Wdv,  16384); add(23, O_Wf,   16384);
  add(25, O_Wwsrc,16384); add(26, O_Wwtrg,16384);
  add(18, O_Wvec, 49152); add(19, O_Ws,   32768); add(21, O_Wo,   49152);
  add(27, O_Wagg,  8192);
  add(9,  O_bq, 128); add(11, O_bk, 128); add(13, O_bv, 128); add(15, O_bdk, 128);
  add(17, O_bdv, 128); add(20, O_bs, 256); add(22, O_bo, 384); add(24, O_bf, 128);
  add(6,  O_lng, 128); add(7,  O_lnb, 128); add(28, O_agg, 1);
  p.cnt = c;

  hipMemsetAsync(ws, 0, 33554432, stream);              // zero xacc+vacc
  hipMemsetAsync(ws + CNT_OFF, 0, 65536, stream);       // zero cnt
  k_hist<<<dim3(NE/256), 256, 0, stream>>>(ei, cnt);
  k_scan<<<dim3(1), 1024, 0, stream>>>(cnt, cur);
  k_place<<<dim3(NE/256), 256, 0, stream>>>(ei, cur, se);
  k_cvt<<<dim3(128), 256, 0, stream>>>(p, wsu);
  k_ln<<<dim3(NN/4), 256, 0, stream>>>(x, wsu, xn);
  k_gemm_qkv<<<dim3(NN/16, 6), 256, 0, stream>>>(xn, wsu, qkv);
  k_gemm_vec<<<dim3(3*NN/16), 256, 0, stream>>>(vecf, wsu, v12, vec3, Ybuf);
  k_edge<<<dim3(NE/64), 256, 0, stream>>>(f_ij, wsu, qkv, Ybuf, ei, se, r_ij, d_ij,
                                          vecf, aggf, df, xacc, vacc);
  k_update<<<dim3(NN/16, 2), 256, 0, stream>>>(xacc, wsu, v12, vec3, vacc, dx, dvec);
}

// Round 11
// 421.156 us; speedup vs baseline: 9.7177x; 1.0177x over previous
//
#include <hip/hip_runtime.h>

#define NN 16384
#define NE 131072
#define HH 128

typedef unsigned short u16;
typedef unsigned int u32;
typedef __attribute__((ext_vector_type(8))) short short8;
typedef __attribute__((ext_vector_type(4))) float f32x4;
typedef __attribute__((ext_vector_type(2))) float f32x2;
typedef __attribute__((ext_vector_type(2))) u32 u32x2;

__device__ __forceinline__ float b2f(u16 u){ u32 i=((u32)u)<<16; float f; __builtin_memcpy(&f,&i,4); return f; }
__device__ __forceinline__ u16 f2b(float f){ u32 i; __builtin_memcpy(&i,&f,4); u32 r=(i+0x7fffu+((i>>16)&1u))>>16; return (u16)r; }
__device__ __forceinline__ float blo(u32 v){ return b2f((u16)(v&0xffffu)); }
__device__ __forceinline__ float bhi(u32 v){ return b2f((u16)(v>>16)); }
__device__ __forceinline__ u32 pk(float a, float b){ return (u32)f2b(a) | ((u32)f2b(b)<<16); }
__device__ __forceinline__ float siluf(float x){ return x/(1.f+__expf(-x)); }

// LDS XOR swizzles (row width 256B / 512B); applied per-phase (each phase rewrites before reading)
#define SW8(b) ((b) ^ ((((b)>>8)&7)<<4))
#define SW9(b) ((b) ^ ((((b)>>9)&7)<<4))

// ws byte layout:
//   0          : xacc f32 [N,128] (8MB)
//   8388608    : vacc f32 [3N,128] (25MB) -> end 33,554,432
//   33554432   : Y [3N,256] bf16 (25MB)
//   58720256   : xn [N,128] bf16 (4MB)
//   67108864   : vec3 [3N,128] bf16 (12.6MB)
//   79691776   : qkv [N,384] bf16 (12.6MB)
//   92274688   : v12 [3N,256] bf16 (25MB) -> 117,440,512
//   117440512  : params bf16 (~545KB)
//   117985280  : cnt int[16384]; 118050816 cur; 118116352 se int[E]
#define PBASE 58720256u   // u16 units = byte 117,440,512
enum : unsigned {
  O_Wq=PBASE+0, O_Wk=PBASE+16384, O_Wv=PBASE+32768, O_Wdk=PBASE+49152,
  O_Wdv=PBASE+65536, O_Wf=PBASE+81920, O_Wwsrc=PBASE+98304, O_Wwtrg=PBASE+114688,
  O_Wvec=PBASE+131072, O_Ws=PBASE+180224, O_Wo=PBASE+212992, O_Wagg=PBASE+262144,
  O_bq=PBASE+270336, O_bk=PBASE+270464, O_bv=PBASE+270592, O_bdk=PBASE+270720,
  O_bdv=PBASE+270848, O_bs=PBASE+270976, O_bo=PBASE+271232, O_bf=PBASE+271616,
  O_lng=PBASE+271744, O_lnb=PBASE+271872, O_agg=PBASE+272000
};
#define CNT_OFF 117985280u
#define CUR_OFF 118050816u
#define SE_OFF  118116352u

struct Seg { const float* s; u32 off; u32 n; };
struct Pack { Seg d[25]; int cnt; };

// ---------------- f32 -> bf16 conversion (params only) ----------------
__global__ __launch_bounds__(256) void k_cvt(Pack p, u16* __restrict__ base){
  int tid = blockIdx.x*blockDim.x + threadIdx.x;
  int stride = gridDim.x*blockDim.x;
  for (int s=0; s<p.cnt; ++s){
    const float* src = p.d[s].s;
    u16* dst = base + p.d[s].off;
    int n = (int)p.d[s].n, n4 = n>>2;
    const f32x4* s4 = (const f32x4*)src;
    for (int i=tid; i<n4; i+=stride){
      f32x4 v = s4[i];
      u32x2 o; o[0] = pk(v[0], v[1]); o[1] = pk(v[2], v[3]);
      *(u32x2*)(dst + 4*(size_t)i) = o;
    }
    for (int i = n4*4 + tid; i < n; i += stride) dst[i] = f2b(src[i]);
  }
}

// ---------------- edge sort by dst: histogram, scan, place ----------------
__global__ __launch_bounds__(256) void k_hist(const int* __restrict__ ei, int* __restrict__ cnt){
  int e = blockIdx.x*256 + threadIdx.x;
  atomicAdd(&cnt[ei[NE + e]], 1);
}
__global__ __launch_bounds__(1024) void k_scan(const int* __restrict__ cnt, int* __restrict__ cur){
  __shared__ int part[1024];
  int t = threadIdx.x;
  int base = t*16;
  int local[16]; int s = 0;
#pragma unroll
  for (int k=0;k<16;++k){ local[k] = cnt[base+k]; s += local[k]; }
  part[t] = s;
  __syncthreads();
  for (int d=1; d<1024; d<<=1){
    int v = (t>=d) ? part[t-d] : 0;
    __syncthreads();
    part[t] += v;
    __syncthreads();
  }
  int run = (t>0) ? part[t-1] : 0;
#pragma unroll
  for (int k=0;k<16;++k){ cur[base+k] = run; run += local[k]; }
}
__global__ __launch_bounds__(256) void k_place(const int* __restrict__ ei, int* __restrict__ cur,
                                               int* __restrict__ se){
  int e = blockIdx.x*256 + threadIdx.x;
  int p = atomicAdd(&cur[ei[NE + e]], 1);
  se[p] = e;
}

// one 16x16 output tile helper (A/W bf16 row-major)
template<int NK>
__device__ __forceinline__ f32x4 mm16(const u16* A, int lda, const u16* W, int ldw, f32x4 acc){
  int lane = threadIdx.x & 63;
  const u16* pa = A + (lane & 15)*lda + ((lane>>4)<<3);
  const u16* pw = W + (lane & 15)*ldw + ((lane>>4)<<3);
#pragma unroll
  for (int kc = 0; kc < NK; ++kc){
    short8 a = *(const short8*)(pa + kc*32);
    short8 b = *(const short8*)(pw + kc*32);
    acc = __builtin_amdgcn_mfma_f32_16x16x32_bf16(a, b, acc, 0, 0, 0);
  }
  return acc;
}

// ---------------- LayerNorm (f32 in -> bf16 out) ----------------
__global__ __launch_bounds__(256) void k_ln(const float* __restrict__ x, const u16* __restrict__ pb,
                                            u16* __restrict__ xn){
  int wid = threadIdx.x>>6, lane = threadIdx.x & 63;
  int n = blockIdx.x*4 + wid;
  f32x2 v = *(const f32x2*)(x + (size_t)n*HH + 2*lane);
  float a0 = v[0], a1 = v[1];
  float s = a0 + a1;
#pragma unroll
  for (int m=32; m; m>>=1) s += __shfl_xor(s, m);
  float mu = s*(1.f/128.f);
  float d0 = a0-mu, d1 = a1-mu;
  float vs = d0*d0 + d1*d1;
#pragma unroll
  for (int m=32; m; m>>=1) vs += __shfl_xor(vs, m);
  float rs = rsqrtf(vs*(1.f/128.f) + 1e-5f);
  u32 gg = *(const u32*)(pb + O_lng + 2*lane);
  u32 bb = *(const u32*)(pb + O_lnb + 2*lane);
  *(u32*)(xn + (size_t)n*HH + 2*lane) = pk(d0*rs*blo(gg)+blo(bb), d1*rs*bhi(gg)+bhi(bb));
}

// ---------------- qkv = xn @ [Wq|Wk|Wv]^T + b ----------------
__global__ __launch_bounds__(256) void k_gemm_qkv(const u16* __restrict__ xn,
    const u16* __restrict__ pb, u16* __restrict__ qkv){
  int wid = threadIdx.x>>6, lane = threadIdx.x & 63;
  int ct = blockIdx.y*4 + wid;          // 0..23
  int r0 = blockIdx.x*16;
  unsigned wo, bo_;
  if (ct < 8)      { wo = O_Wq; bo_ = O_bq; }
  else if (ct <16) { wo = O_Wk; bo_ = O_bk; }
  else             { wo = O_Wv; bo_ = O_bv; }
  int c0 = (ct & 7)*16;
  f32x4 acc = {0,0,0,0};
  acc = mm16<4>(xn + (size_t)r0*HH, HH, pb + wo + c0*HH, HH, acc);
  int col = ct*16 + (lane & 15);
  float bb = b2f(pb[bo_ + c0 + (lane&15)]);
#pragma unroll
  for (int j=0;j<4;++j){
    int r = r0 + ((lane>>4)<<2) + j;
    qkv[(size_t)r*384 + col] = f2b(acc[j] + bb);
  }
}

// ---------------- vec GEMMs: stage 16 rows of vec (f32->bf16 LDS), all 40 col-tiles ----------------
__global__ __launch_bounds__(256) void k_gemm_vec(const float* __restrict__ vecf,
    const u16* __restrict__ pb,
    u16* __restrict__ v12, u16* __restrict__ vec3, u16* __restrict__ Y){
  __shared__ u16 At[16*128];
  int tid = threadIdx.x, wid = tid>>6, lane = tid & 63;
  int r0 = blockIdx.x*16;               // rows in [3N]
  {
    const float* src = vecf + (size_t)r0*HH;
    for (int i = tid*4; i < 2048; i += 1024){
      f32x4 v = *(const f32x4*)(src + i);
      u32x2 o; o[0] = pk(v[0], v[1]); o[1] = pk(v[2], v[3]);
      *(u32x2*)(At + i) = o;
    }
  }
  __syncthreads();
  for (int ct = wid; ct < 40; ct += 4){
    unsigned wo; int wc0;
    if (ct < 24)      { wo = O_Wvec;  wc0 = ct*16; }
    else if (ct < 32) { wo = O_Wwsrc; wc0 = (ct-24)*16; }
    else              { wo = O_Wwtrg; wc0 = (ct-32)*16; }
    f32x4 acc = {0,0,0,0};
    acc = mm16<4>(At, HH, pb + wo + wc0*HH, HH, acc);
    u16* dst; int ldc, dc0;
    if (ct < 16)      { dst = v12;  ldc = 256; dc0 = ct*16; }           // vec1|vec2
    else if (ct < 24) { dst = vec3; ldc = 128; dc0 = (ct-16)*16; }      // vec3
    else if (ct < 32) { dst = Y;    ldc = 256; dc0 = (ct-24)*16; }      // Ysrc
    else              { dst = Y;    ldc = 256; dc0 = (ct-32)*16 + 128; }// Ytrg
    int col = dc0 + (lane & 15);
#pragma unroll
    for (int j=0;j<4;++j){
      int r = r0 + ((lane>>4)<<2) + j;
      dst[(size_t)r*ldc + col] = f2b(acc[j]);
    }
  }
}

// ---------------- FUSED edge kernel (dst-sorted, zero barriers, wave-local LDS, swizzled) ----------------
__global__ __launch_bounds__(256) void k_edge(const float* __restrict__ f_ij,
    const u16* __restrict__ pb,
    const u16* __restrict__ qkv, const u16* __restrict__ Y,
    const int* __restrict__ ei, const int* __restrict__ se,
    const float* __restrict__ r_ij, const float* __restrict__ d_ij,
    const float* __restrict__ vecf, const float* __restrict__ aggf,
    float* __restrict__ df, float* __restrict__ xacc, float* __restrict__ vacc){
  __shared__ u16 fs[64*128];
  __shared__ u16 g2s[64*256];
  char* fsb  = (char*)fs;
  char* g2b  = (char*)g2s;
  int tid = threadIdx.x, wid = tid>>6, lane = tid & 63;
  int t0 = blockIdx.x*64;
  int ereg=0, dreg=0, sreg=0;
  if (lane < 16){
    ereg = se[t0 + wid*16 + lane];
    dreg = ei[NE + ereg];
    sreg = ei[ereg];
  }
  // ---- stage this wave's 16 sorted f_ij rows into fs (wave-local, swizzled) ----
#pragma unroll
  for (int pass=0; pass<8; ++pass){
    int idx = pass*256 + lane*4;          // f32 index within wave's 16 rows
    int rloc = idx >> 7, col = idx & 127;
    int er = __shfl(ereg, rloc);
    f32x4 v = *(const f32x4*)(f_ij + (size_t)er*HH + col);
    u32x2 o; o[0]=pk(v[0],v[1]); o[1]=pk(v[2],v[3]);
    int b = (wid*16 + rloc)*256 + col*2;
    *(u32x2*)(fsb + SW8(b)) = o;
  }
  // ---- phase A: dk/dv/ff GEMMs from fs fragments ----
  {
    int arow = wid*16 + (lane&15);
    int ab = arow*256 + ((lane>>4)<<4);
    short8 a0 = *(const short8*)(fsb + SW8(ab));
    short8 a1 = *(const short8*)(fsb + SW8(ab + 64));
    short8 a2 = *(const short8*)(fsb + SW8(ab + 128));
    short8 a3 = *(const short8*)(fsb + SW8(ab + 192));
    for (int ct=0; ct<16; ++ct){
      unsigned wo  = (ct<8) ? O_Wdk : O_Wdv;
      unsigned bo_ = (ct<8) ? O_bdk : O_bdv;
      int c0 = (ct&7)*16;
      const u16* pw = pb + wo + (size_t)(c0 + (lane&15))*HH + ((lane>>4)<<3);
      f32x4 acc = {0,0,0,0};
      acc = __builtin_amdgcn_mfma_f32_16x16x32_bf16(a0, *(const short8*)(pw),      acc, 0,0,0);
      acc = __builtin_amdgcn_mfma_f32_16x16x32_bf16(a1, *(const short8*)(pw + 32), acc, 0,0,0);
      acc = __builtin_amdgcn_mfma_f32_16x16x32_bf16(a2, *(const short8*)(pw + 64), acc, 0,0,0);
      acc = __builtin_amdgcn_mfma_f32_16x16x32_bf16(a3, *(const short8*)(pw + 96), acc, 0,0,0);
      float bb = b2f(pb[bo_ + c0 + (lane&15)]);
#pragma unroll
      for (int j=0;j<4;++j){
        int r = wid*16 + ((lane>>4)<<2) + j;
        int b = r*512 + (ct*16 + (lane&15))*2;
        *(u16*)(g2b + SW9(b)) = f2b(siluf(acc[j] + bb));
      }
    }
    f32x4 ffa[8];
#pragma unroll
    for (int cf=0; cf<8; ++cf){
      const u16* pw = pb + O_Wf + (size_t)(cf*16 + (lane&15))*HH + ((lane>>4)<<3);
      f32x4 acc = {0,0,0,0};
      acc = __builtin_amdgcn_mfma_f32_16x16x32_bf16(a0, *(const short8*)(pw),      acc, 0,0,0);
      acc = __builtin_amdgcn_mfma_f32_16x16x32_bf16(a1, *(const short8*)(pw + 32), acc, 0,0,0);
      acc = __builtin_amdgcn_mfma_f32_16x16x32_bf16(a2, *(const short8*)(pw + 64), acc, 0,0,0);
      acc = __builtin_amdgcn_mfma_f32_16x16x32_bf16(a3, *(const short8*)(pw + 96), acc, 0,0,0);
      ffa[cf] = acc;
    }
#pragma unroll
    for (int cf=0; cf<8; ++cf){
      float bb = b2f(pb[O_bf + cf*16 + (lane&15)]);
#pragma unroll
      for (int j=0;j<4;++j){
        int r = wid*16 + ((lane>>4)<<2) + j;
        int b = r*256 + (cf*16 + (lane&15))*2;
        *(u16*)(fsb + SW8(b)) = f2b(siluf(ffa[cf][j] + bb));
      }
    }
  }
  // ---- phase B: attn + vmsg(->fs) + df, prefetched src gathers + dst-run caching ----
  int h0 = 2*lane;
  {
    int pdst = -1; u32 qq=0, ya0=0, ya1=0, ya2=0;
    int e_c = __shfl(ereg, 0), src_c = __shfl(sreg, 0);
    u32 kk_c  = *(const u32*)(qkv + (size_t)src_c*384 + 128 + h0);
    u32 vv_c  = *(const u32*)(qkv + (size_t)src_c*384 + 256 + h0);
    u32 yb0_c = *(const u32*)(Y + ((size_t)src_c*3+0)*256 + h0);
    u32 yb1_c = *(const u32*)(Y + ((size_t)src_c*3+1)*256 + h0);
    u32 yb2_c = *(const u32*)(Y + ((size_t)src_c*3+2)*256 + h0);
    float r_c   = r_ij[e_c];
    float dc0_c = d_ij[(size_t)e_c*3+0];
    float dc1_c = d_ij[(size_t)e_c*3+1];
    float dc2_c = d_ij[(size_t)e_c*3+2];
    for (int i=0;i<16;++i){
      int e = e_c;
      u32 kk=kk_c, vv=vv_c, yb0=yb0_c, yb1=yb1_c, yb2=yb2_c;
      float r=r_c, dc0=dc0_c, dc1=dc1_c, dc2=dc2_c;
      if (i<15){
        int e_n = __shfl(ereg, i+1), src_n = __shfl(sreg, i+1);
        kk_c  = *(const u32*)(qkv + (size_t)src_n*384 + 128 + h0);
        vv_c  = *(const u32*)(qkv + (size_t)src_n*384 + 256 + h0);
        yb0_c = *(const u32*)(Y + ((size_t)src_n*3+0)*256 + h0);
        yb1_c = *(const u32*)(Y + ((size_t)src_n*3+1)*256 + h0);
        yb2_c = *(const u32*)(Y + ((size_t)src_n*3+2)*256 + h0);
        r_c   = r_ij[e_n];
        dc0_c = d_ij[(size_t)e_n*3+0];
        dc1_c = d_ij[(size_t)e_n*3+1];
        dc2_c = d_ij[(size_t)e_n*3+2];
        e_c = e_n;
      }
      int el = wid*16 + i;
      int dst = __shfl(dreg, i);
      if (dst != pdst){
        qq  = *(const u32*)(qkv + (size_t)dst*384 + h0);
        ya0 = *(const u32*)(Y + ((size_t)dst*3+0)*256 + 128 + h0);
        ya1 = *(const u32*)(Y + ((size_t)dst*3+1)*256 + 128 + h0);
        ya2 = *(const u32*)(Y + ((size_t)dst*3+2)*256 + 128 + h0);
        pdst = dst;
      }
      int bdk = el*512 + h0*2;
      u32 dk = *(const u32*)(g2b + SW9(bdk));
      u32 dv = *(const u32*)(g2b + SW9(bdk + 256));
      int bff = el*256 + h0*2;
      u32 ff = *(const u32*)(fsb + SW8(bff));
      float p = blo(qq)*blo(kk)*blo(dk) + bhi(qq)*bhi(kk)*bhi(dk);
      p += __shfl_xor(p,1); p += __shfl_xor(p,2); p += __shfl_xor(p,4);
      float cut = 0.5f*(__cosf(0.6283185307f*r)+1.f) * (r < 5.f ? 1.f : 0.f);
      float attn = siluf(p)*cut;
      float m0 = blo(vv)*blo(dv)*attn, m1 = bhi(vv)*bhi(dv)*attn;
      float ab0,ab1, ad0,ad1, bd0,bd1, ss;
      ab0 = blo(ya0)*blo(yb0); ab1 = bhi(ya0)*bhi(yb0);
      ad0 = blo(ya0)*dc0;      ad1 = bhi(ya0)*dc0;
      bd0 = blo(yb0)*dc0;      bd1 = bhi(yb0)*dc0;
      ss  = dc0*dc0;
      ab0 += blo(ya1)*blo(yb1); ab1 += bhi(ya1)*bhi(yb1);
      ad0 += blo(ya1)*dc1;      ad1 += bhi(ya1)*dc1;
      bd0 += blo(yb1)*dc1;      bd1 += bhi(yb1)*dc1;
      ss  += dc1*dc1;
      ab0 += blo(ya2)*blo(yb2); ab1 += bhi(ya2)*bhi(yb2);
      ad0 += blo(ya2)*dc2;      ad1 += bhi(ya2)*dc2;
      bd0 += blo(yb2)*dc2;      bd1 += bhi(yb2)*dc2;
      ss  += dc2*dc2;
      float t = 2.f - ss;
      f32x2 dfo; dfo[0] = blo(ff)*(ab0 - ad0*bd0*t); dfo[1] = bhi(ff)*(ab1 - ad1*bd1*t);
      *(f32x2*)(df + (size_t)e*HH + h0) = dfo;
      *(u32*)(fsb + SW8(bff)) = pk(m0, m1);   // vmsg into fs
    }
  }
  float absA = fabsf(aggf[0]);
  // ---- phase C1: ex GEMM (A rows from fs vmsg) -> g2s as [128]x256B (swizzled SW8) ----
#pragma unroll
  for (int rr=0; rr<2; ++rr){
    int rt = wid*2 + rr;
    int el2 = wid*16 + 8*rr + ((lane&15)>>1);
    int pb2 = el2*256 + ((lane&15)&1)*128 + ((lane>>4)<<4);
    short8 b0 = *(const short8*)(fsb + SW8(pb2));
    short8 b1 = *(const short8*)(fsb + SW8(pb2 + 64));
    for (int ct=0; ct<8; ++ct){
      const u16* pw = pb + O_Wagg + (size_t)(ct*16 + (lane&15))*64 + ((lane>>4)<<3);
      f32x4 acc = {0,0,0,0};
      acc = __builtin_amdgcn_mfma_f32_16x16x32_bf16(b0, *(const short8*)(pw),      acc, 0,0,0);
      acc = __builtin_amdgcn_mfma_f32_16x16x32_bf16(b1, *(const short8*)(pw + 32), acc, 0,0,0);
#pragma unroll
      for (int j=0;j<4;++j){
        int r = rt*16 + ((lane>>4)<<2) + j;
        int b = r*256 + (ct*16 + (lane&15))*2;
        *(u16*)(g2b + SW8(b)) = f2b(fminf(fmaxf(acc[j],0.f),1.f));
      }
    }
  }
  // ---- scatter-x (run-merged): reads fs (vmsg) + g2s (ex) ----
  {
    int rdst = -1; float xc0=0.f, xc1=0.f;
    for (int i=0;i<16;++i){
      int el = wid*16 + i;
      int dst = __shfl(dreg, i);
      if (dst != rdst){
        if (rdst >= 0){
          atomicAdd(&xacc[(size_t)rdst*HH + h0],     xc0);
          atomicAdd(&xacc[(size_t)rdst*HH + h0 + 1], xc1);
        }
        rdst = dst; xc0 = xc1 = 0.f;
      }
      int bm = el*256;
      u32 mm = *(const u32*)(fsb + SW8(bm + h0*2));
      u32 ml = *(const u32*)(fsb + SW8(bm + (h0&63)*2));
      u32 mh = *(const u32*)(fsb + SW8(bm + 128 + (h0&63)*2));
      u32 ex0 = *(const u32*)(g2b + SW8((2*el)*256 + h0*2));
      u32 ex1 = *(const u32*)(g2b + SW8((2*el+1)*256 + h0*2));
      xc0 += blo(mm) + absA*(blo(ml)*blo(ex0) + blo(mh)*blo(ex1));
      xc1 += bhi(mm) + absA*(bhi(ml)*bhi(ex0) + bhi(mh)*bhi(ex1));
    }
    if (rdst >= 0){
      atomicAdd(&xacc[(size_t)rdst*HH + h0],     xc0);
      atomicAdd(&xacc[(size_t)rdst*HH + h0 + 1], xc1);
    }
  }
  // ---- phase C2: s GEMM (A=fs vmsg rows) -> g2s as [64]x512B (SW9) ----
  {
    int arow = wid*16 + (lane&15);
    int ab = arow*256 + ((lane>>4)<<4);
    short8 sa0 = *(const short8*)(fsb + SW8(ab));
    short8 sa1 = *(const short8*)(fsb + SW8(ab + 64));
    short8 sa2 = *(const short8*)(fsb + SW8(ab + 128));
    short8 sa3 = *(const short8*)(fsb + SW8(ab + 192));
    for (int ct=0; ct<16; ++ct){
      const u16* pw = pb + O_Ws + (size_t)(ct*16 + (lane&15))*HH + ((lane>>4)<<3);
      f32x4 acc = {0,0,0,0};
      acc = __builtin_amdgcn_mfma_f32_16x16x32_bf16(sa0, *(const short8*)(pw),      acc, 0,0,0);
      acc = __builtin_amdgcn_mfma_f32_16x16x32_bf16(sa1, *(const short8*)(pw + 32), acc, 0,0,0);
      acc = __builtin_amdgcn_mfma_f32_16x16x32_bf16(sa2, *(const short8*)(pw + 64), acc, 0,0,0);
      acc = __builtin_amdgcn_mfma_f32_16x16x32_bf16(sa3, *(const short8*)(pw + 96), acc, 0,0,0);
      float bb = b2f(pb[O_bs + ct*16 + (lane&15)]);
#pragma unroll
      for (int j=0;j<4;++j){
        int r = wid*16 + ((lane>>4)<<2) + j;
        int b = r*512 + (ct*16 + (lane&15))*2;
        *(u16*)(g2b + SW9(b)) = f2b(siluf(acc[j] + bb));
      }
    }
  }
  // ---- scatter-v (run-merged, prefetched vec/d gathers) ----
  {
    int rdst = -1;
    float vc00=0.f,vc01=0.f, vc10=0.f,vc11=0.f, vc20=0.f,vc21=0.f;
    int e_c = __shfl(ereg, 0), src_c = __shfl(sreg, 0);
    f32x2 v0_c = *(const f32x2*)(vecf + ((size_t)src_c*3+0)*HH + h0);
    f32x2 v1_c = *(const f32x2*)(vecf + ((size_t)src_c*3+1)*HH + h0);
    f32x2 v2_c = *(const f32x2*)(vecf + ((size_t)src_c*3+2)*HH + h0);
    float dc0_c = d_ij[(size_t)e_c*3+0];
    float dc1_c = d_ij[(size_t)e_c*3+1];
    float dc2_c = d_ij[(size_t)e_c*3+2];
    for (int i=0;i<16;++i){
      f32x2 vv0=v0_c, vv1=v1_c, vv2=v2_c;
      float dc0=dc0_c, dc1=dc1_c, dc2=dc2_c;
      if (i<15){
        int e_n = __shfl(ereg, i+1), src_n = __shfl(sreg, i+1);
        v0_c = *(const f32x2*)(vecf + ((size_t)src_n*3+0)*HH + h0);
        v1_c = *(const f32x2*)(vecf + ((size_t)src_n*3+1)*HH + h0);
        v2_c = *(const f32x2*)(vecf + ((size_t)src_n*3+2)*HH + h0);
        dc0_c = d_ij[(size_t)e_n*3+0];
        dc1_c = d_ij[(size_t)e_n*3+1];
        dc2_c = d_ij[(size_t)e_n*3+2];
      }
      int el = wid*16 + i;
      int dst = __shfl(dreg, i);
      if (dst != rdst){
        if (rdst >= 0){
          atomicAdd(&vacc[((size_t)rdst*3+0)*HH + h0],     vc00);
          atomicAdd(&vacc[((size_t)rdst*3+0)*HH + h0 + 1], vc01);
          atomicAdd(&vacc[((size_t)rdst*3+1)*HH + h0],     vc10);
          atomicAdd(&vacc[((size_t)rdst*3+1)*HH + h0 + 1], vc11);
          atomicAdd(&vacc[((size_t)rdst*3+2)*HH + h0],     vc20);
          atomicAdd(&vacc[((size_t)rdst*3+2)*HH + h0 + 1], vc21);
        }
        rdst = dst;
        vc00=vc01=vc10=vc11=vc20=vc21=0.f;
      }
      int bs1 = el*512 + h0*2;
      u32 s1 = *(const u32*)(g2b + SW9(bs1));
      u32 s2 = *(const u32*)(g2b + SW9(bs1 + 256));
      vc00 += vv0[0]*blo(s1) + blo(s2)*dc0;  vc01 += vv0[1]*bhi(s1) + bhi(s2)*dc0;
      vc10 += vv1[0]*blo(s1) + blo(s2)*dc1;  vc11 += vv1[1]*bhi(s1) + bhi(s2)*dc1;
      vc20 += vv2[0]*blo(s1) + blo(s2)*dc2;  vc21 += vv2[1]*bhi(s1) + bhi(s2)*dc2;
    }
    if (rdst >= 0){
      atomicAdd(&vacc[((size_t)rdst*3+0)*HH + h0],     vc00);
      atomicAdd(&vacc[((size_t)rdst*3+0)*HH + h0 + 1], vc01);
      atomicAdd(&vacc[((size_t)rdst*3+1)*HH + h0],     vc10);
      atomicAdd(&vacc[((size_t)rdst*3+1)*HH + h0 + 1], vc11);
      atomicAdd(&vacc[((size_t)rdst*3+2)*HH + h0],     vc20);
      atomicAdd(&vacc[((size_t)rdst*3+2)*HH + h0 + 1], vc21);
    }
  }
}

// ---------------- update: o = x_agg @ Wo^T + bo (MFMA); vec_dot inline; f32 out ----------------
__global__ __launch_bounds__(256) void k_update(const float* __restrict__ xacc,
    const u16* __restrict__ pb, const u16* __restrict__ v12, const u16* __restrict__ vec3,
    const float* __restrict__ vacc,
    float* __restrict__ dx, float* __restrict__ dvec){
  int wid = threadIdx.x>>6, lane = threadIdx.x & 63;
  int ct = blockIdx.y*4 + wid;   // 0..7
  int r0 = blockIdx.x*16;
  int c0 = ct*16;
  f32x4 a1 = {0,0,0,0}, a2 = {0,0,0,0}, a3 = {0,0,0,0};
  const float* pa = xacc + (size_t)(r0 + (lane&15))*HH + ((lane>>4)<<3);
#pragma unroll
  for (int kc=0; kc<4; ++kc){
    f32x4 f0 = *(const f32x4*)(pa + kc*32);
    f32x4 f1 = *(const f32x4*)(pa + kc*32 + 4);
    short8 av;
    av[0]=(short)f2b(f0[0]); av[1]=(short)f2b(f0[1]); av[2]=(short)f2b(f0[2]); av[3]=(short)f2b(f0[3]);
    av[4]=(short)f2b(f1[0]); av[5]=(short)f2b(f1[1]); av[6]=(short)f2b(f1[2]); av[7]=(short)f2b(f1[3]);
    const u16* pw = pb + O_Wo + (size_t)(c0 + (lane&15))*HH + ((lane>>4)<<3) + kc*32;
    short8 b1 = *(const short8*)(pw);
    short8 b2 = *(const short8*)(pw + 128*HH);
    short8 b3 = *(const short8*)(pw + 256*HH);
    a1 = __builtin_amdgcn_mfma_f32_16x16x32_bf16(av, b1, a1, 0,0,0);
    a2 = __builtin_amdgcn_mfma_f32_16x16x32_bf16(av, b2, a2, 0,0,0);
    a3 = __builtin_amdgcn_mfma_f32_16x16x32_bf16(av, b3, a3, 0,0,0);
  }
  int h = c0 + (lane & 15);
  float bo1 = b2f(pb[O_bo + h]), bo2 = b2f(pb[O_bo + 128 + h]), bo3 = b2f(pb[O_bo + 256 + h]);
#pragma unroll
  for (int j=0;j<4;++j){
    int r = r0 + ((lane>>4)<<2) + j;
    float o1 = a1[j]+bo1, o2 = a2[j]+bo2, o3 = a3[j]+bo3;
    float vdot = 0.f;
#pragma unroll
    for (int c=0;c<3;++c){
      const u16* row = v12 + ((size_t)r*3 + c)*256;
      vdot += b2f(row[h]) * b2f(row[128 + h]);
    }
    dx[(size_t)r*HH + h] = vdot*o2 + o3;
#pragma unroll
    for (int c=0;c<3;++c){
      size_t idx = ((size_t)r*3+c)*HH + h;
      dvec[idx] = b2f(vec3[idx])*o1 + vacc[idx];
    }
  }
}

extern "C" void kernel_launch(void* const* d_in, const int* in_sizes, int n_in,
                              void* d_out, int out_size, void* d_ws, size_t ws_size,
                              hipStream_t stream){
  (void)in_sizes; (void)n_in; (void)out_size; (void)ws_size;
  const float* x     = (const float*)d_in[0];
  const float* vecf  = (const float*)d_in[1];
  const int*   ei    = (const int*)d_in[2];
  const float* r_ij  = (const float*)d_in[3];
  const float* f_ij  = (const float*)d_in[4];
  const float* d_ij  = (const float*)d_in[5];
  const float* aggf  = (const float*)d_in[28];

  char* ws = (char*)d_ws;
  u16*   wsu   = (u16*)d_ws;
  float* xacc  = (float*)(ws + 0);          // [N,128] f32
  float* vacc  = (float*)(ws + 8388608);    // [3N,128] f32
  u16*   Ybuf  = (u16*)(ws + 33554432);     // [3N,256] bf16
  u16*   xn    = (u16*)(ws + 58720256);     // [N,128] bf16
  u16*   vec3  = (u16*)(ws + 67108864);     // [3N,128] bf16
  u16*   qkv   = (u16*)(ws + 79691776);     // [N,384] bf16
  u16*   v12   = (u16*)(ws + 92274688);     // [3N,256] bf16
  int*   cnt   = (int*)(ws + CNT_OFF);
  int*   cur   = (int*)(ws + CUR_OFF);
  int*   se    = (int*)(ws + SE_OFF);

  float* out  = (float*)d_out;
  float* dx   = out;
  float* dvec = out + (size_t)NN*128;
  float* df   = out + (size_t)NN*512;

  Pack p; int c = 0;
  auto add = [&](int idx, unsigned off, unsigned n){ p.d[c].s=(const float*)d_in[idx]; p.d[c].off=off; p.d[c].n=n; ++c; };
  add(8,  O_Wq,   16384); add(10, O_Wk,   16384); add(12, O_Wv,   16384);
  add(14, O_Wdk,  16384); add(16, O_Wdv,  16384); add(23, O_Wf,   16384);
  add(25, O_Wwsrc,16384); add(26, O_Wwtrg,16384);
  add(18, O_Wvec, 49152); add(19, O_Ws,   32768); add(21, O_Wo,   49152);
  add(27, O_Wagg,  8192);
  add(9,  O_bq, 128); add(11, O_bk, 128); add(13, O_bv, 128); add(15, O_bdk, 128);
  add(17, O_bdv, 128); add(20, O_bs, 256); add(22, O_bo, 384); add(24, O_bf, 128);
  add(6,  O_lng, 128); add(7,  O_lnb, 128); add(28, O_agg, 1);
  p.cnt = c;

  hipMemsetAsync(ws, 0, 33554432, stream);              // zero xacc+vacc
  hipMemsetAsync(ws + CNT_OFF, 0, 65536, stream);       // zero cnt
  k_hist<<<dim3(NE/256), 256, 0, stream>>>(ei, cnt);
  k_scan<<<dim3(1), 1024, 0, stream>>>(cnt, cur);
  k_place<<<dim3(NE/256), 256, 0, stream>>>(ei, cur, se);
  k_cvt<<<dim3(128), 256, 0, stream>>>(p, wsu);
  k_ln<<<dim3(NN/4), 256, 0, stream>>>(x, wsu, xn);
  k_gemm_qkv<<<dim3(NN/16, 6), 256, 0, stream>>>(xn, wsu, qkv);
  k_gemm_vec<<<dim3(3*NN/16), 256, 0, stream>>>(vecf, wsu, v12, vec3, Ybuf);
  k_edge<<<dim3(NE/64), 256, 0, stream>>>(f_ij, wsu, qkv, Ybuf, ei, se, r_ij, d_ij,
                                          vecf, aggf, df, xacc, vacc);
  k_update<<<dim3(NN/16, 2), 256, 0, stream>>>(xacc, wsu, v12, vec3, vacc, dx, dvec);
}